// Round 16
// baseline (778.220 us; speedup 1.0000x reference)
//
#include <hip/hip_runtime.h>
#include <hip/hip_bf16.h>
#include <math.h>

#define B_ 8
#define N_ 384
#define F_ 64
#define H_ 128
#define LN_EPS 1e-5f

typedef _Float16 f16;
typedef f16 f16x2 __attribute__((ext_vector_type(2)));
typedef f16 f16x4 __attribute__((ext_vector_type(4)));
typedef f16 f16x8 __attribute__((ext_vector_type(8)));
typedef float f32x4v __attribute__((ext_vector_type(4)));

static __device__ __forceinline__ f16x2 u2h(unsigned int u) {
    union { unsigned int u; f16x2 h; } c; c.u = u; return c.h;
}
static __device__ __forceinline__ unsigned int h2u(f16 a, f16 b) {
    union { f16x2 h; unsigned int u; } c; c.h = (f16x2){a, b}; return c.u;
}

// packed-permuted index helpers: uint slot u = h4*16 + mf*2 + p packs
// elements (n, n+1) with n = mf*16 + h4*4 + 2p  (matches MFMA C/D row layout)
static __device__ __forceinline__ void perm_idx(int m, int& u, int& n0) {
    int h4 = (m >> 1) & 3, mf = m >> 3, p = m & 1;
    u = h4 * 16 + mf * 2 + p;
    n0 = mf * 16 + h4 * 4 + 2 * p;
}

// -------------------- fused setup kernel --------------------
__global__ __launch_bounds__(128) void k_prep(
    const float* __restrict__ inp, const float* __restrict__ sW1,
    const float* __restrict__ vb2, const float* __restrict__ sb1,
    const float* __restrict__ vW2, const float* __restrict__ vW1,
    const float* __restrict__ vb1, const float* __restrict__ vg,
    const float* __restrict__ vbeta, const float* __restrict__ sW2,
    unsigned int* __restrict__ t16, unsigned short* __restrict__ W2hT,
    unsigned int* __restrict__ coeffP, float* __restrict__ scal,
    unsigned int* __restrict__ sw16) {
    __shared__ float red[128];
    __shared__ float caS[128], cbS[128], ccS[128];
    const int bx = blockIdx.x;
    const int tid = threadIdx.x;

    if (bx < B_ * N_) {
        // tt[n] = 0.25*(in[row]+vb2)@sW1[:,n] + 0.5*sb1[n] ; pack-permute to t16
        int row = bx, n = tid;
        float acc = 0.f;
#pragma unroll
        for (int f = 0; f < F_; ++f)
            acc = fmaf(0.25f * (inp[row * F_ + f] + vb2[f]), sW1[f * H_ + n], acc);
        red[n] = acc + 0.5f * sb1[n];
        __syncthreads();
        if (tid < 64) {
            int u, n0; perm_idx(tid, u, n0);
            t16[row * 64 + u] = h2u((f16)red[n0], (f16)red[n0 + 1]);
        }
        return;
    }
    if (bx < B_ * N_ + 128) {
        int idx = (bx - B_ * N_) * 128 + tid;
        int k = idx >> 7, n = idx & 127;
        float acc = 0.f;
#pragma unroll
        for (int f = 0; f < F_; ++f) acc = fmaf(vW2[k * F_ + f], sW1[f * H_ + n], acc);
        f16 hv = (f16)(0.5f * acc);
        W2hT[n * H_ + k] = *reinterpret_cast<unsigned short*>(&hv);
        return;
    }

    // ---- algebraic-LN coefficients + sw16 ----
    const int d = tid;   // 128
    float a = vW1[d], bb = vW1[H_ + d], c = vb1[d];
    float mA, mB, mC, Saa, Sbb, Scc, Sab, Sac, Sbc;
    float ca, cb, cc;
#define BMEAN(OUT, VAL)                                                  \
    red[d] = (VAL); __syncthreads();                                     \
    for (int st = 64; st > 0; st >>= 1) {                                \
        if (d < st) red[d] += red[d + st];                               \
        __syncthreads();                                                 \
    }                                                                    \
    OUT = red[0] * (1.f / 128.f); __syncthreads();

    BMEAN(mA, a); BMEAN(mB, bb); BMEAN(mC, c);
    ca = a - mA; cb = bb - mB; cc = c - mC;
    caS[d] = ca * vg[d]; cbS[d] = cb * vg[d]; ccS[d] = cc * vg[d];
    BMEAN(Saa, ca * ca); BMEAN(Sbb, cb * cb); BMEAN(Scc, cc * cc);
    BMEAN(Sab, ca * cb); BMEAN(Sac, ca * cc); BMEAN(Sbc, cb * cc);
#undef BMEAN
    __syncthreads();
    if (d < 64) {
        int d0 = 2 * d;
        coeffP[d]       = h2u((f16)caS[d0], (f16)caS[d0 + 1]);
        coeffP[64 + d]  = h2u((f16)cbS[d0], (f16)cbS[d0 + 1]);
        coeffP[128 + d] = h2u((f16)ccS[d0], (f16)ccS[d0 + 1]);
        coeffP[192 + d] = h2u((f16)vbeta[d0], (f16)vbeta[d0 + 1]);
        int u, n0; perm_idx(d, u, n0);
        sw16[u] = h2u((f16)sW2[n0], (f16)sW2[n0 + 1]);
    }
    if (d == 0) {
        scal[0] = Saa; scal[1] = Sbb; scal[2] = Scc;
        scal[3] = Sab; scal[4] = Sac; scal[5] = Sbc;
    }
}

// -------------------- phase 1: scores + flash accH (occupancy push) --------------------
// R15 structure; NEW: LDS 50KB (W' 32KB + vW2 fp16 16KB + coeff copy 1KB) -> 3 blocks/CU,
// and __launch_bounds__(256,3) caps VGPR at 170 WITH an LDS reload path for the coeff
// table (per-tile broadcast b128 reads) so the allocator reloads instead of scratch-spilling.
// Tripwires: VGPR_Count >170 impossible; WRITE_SIZE balloon = scratch spill => revert.
#define VW2_OFF   32768
#define COEFF_OFF 49152
__global__ __launch_bounds__(256, 3) void k_scores(
    const float* __restrict__ pos, const unsigned int* __restrict__ coeffP,
    const float* __restrict__ scal, const unsigned short* __restrict__ W2hT,
    const float* __restrict__ vW2, const unsigned int* __restrict__ t16,
    const unsigned int* __restrict__ sw16, const float* __restrict__ sb2,
    float* __restrict__ scores, float* __restrict__ rowmax,
    float* __restrict__ rowsum, float* __restrict__ xpart) {
    __shared__ __align__(16) char smem[50176];

    const int tid = threadIdx.x;
    const int b = blockIdx.y;
    const int w = tid >> 6, lane = tid & 63;
    const int i = blockIdx.x * 4 + w;
    const int ln = lane & 15, h4 = lane >> 4;

    // ---- one-time stage: W' swizzled + vW2 fp16 + coeff copy ----
#pragma unroll
    for (int s = 0; s < 8; ++s) {
        int idx = tid + s * 256;
        int n = idx >> 4, c = idx & 15;
        uint4 v = *(const uint4*)(W2hT + n * H_ + c * 8);
        *(uint4*)(smem + ((n * 256 + c * 16) ^ ((n & 7) << 4))) = v;
    }
#pragma unroll
    for (int s = 0; s < 16; ++s) {
        int idx = tid + s * 256;            // 0..4095 packed fp16 pairs of vW2 (128x64)
        float2 v = *(const float2*)((const float*)vW2 + idx * 2);
        *(unsigned int*)(smem + VW2_OFF + idx * 4) = h2u((f16)v.x, (f16)v.y);
    }
    ((unsigned int*)(smem + COEFF_OFF))[tid] = coeffP[tid];   // 256 uints
    __syncthreads();

    const unsigned int* cS = (const unsigned int*)(smem + COEFF_OFF);

    // ---- resident state (kept small; coeff reloads from LDS under the reg cap) ----
    unsigned int tih[16];
    {
        const unsigned int* tiP = t16 + (size_t)(b * N_ + i) * 64 + h4 * 16;
#pragma unroll
        for (int s = 0; s < 4; ++s) {
            uint4 v = *(const uint4*)(tiP + s * 4);
            tih[s * 4 + 0] = v.x; tih[s * 4 + 1] = v.y;
            tih[s * 4 + 2] = v.z; tih[s * 4 + 3] = v.w;
        }
    }
    uint2 swR[8];
#pragma unroll
    for (int mf = 0; mf < 8; ++mf)
        swR[mf] = *(const uint2*)(sw16 + h4 * 16 + mf * 2);

    const float Saa = scal[0], Sbb = scal[1], Scc = scal[2];
    const float Sab = scal[3], Sac = scal[4], Sbc = scal[5];
    const float sb2v = sb2[0];

    const float* pi = pos + (size_t)(b * N_ + i) * 3;
    const float ax = pi[0], ay = pi[1], az = pi[2];
    float* scoreRow = scores + (size_t)(b * N_ + i) * N_;

    float m_run = -1e30f, s_run = 0.f;
    float accH[4][8];
#pragma unroll
    for (int kc = 0; kc < 4; ++kc)
#pragma unroll
        for (int e = 0; e < 8; ++e) accH[kc][e] = 0.f;

    // pos prefetch for tile 0
    const float* pj0p = pos + (size_t)(b * N_ + ln) * 3;
    float bx = pj0p[0], by = pj0p[1], bz = pj0p[2];

#pragma unroll 1
    for (int jt = 0; jt < 24; ++jt) {
        const int j0 = jt * 16;

        // ---- tj prefetch (packed), consumed at phaseC ----
        const unsigned int* tjP = t16 + (size_t)(b * N_ + j0 + ln) * 64 + h4 * 16;
        uint4 tj0 = *(const uint4*)(tjP);
        uint4 tj1 = *(const uint4*)(tjP + 4);
        uint4 tj2 = *(const uint4*)(tjP + 8);
        uint4 tj3 = *(const uint4*)(tjP + 12);

        // ---- geometry ----
        float dotv = ax * bx + ay * by + az * bz;
        float cx = ay * bz - az * by;
        float cy = az * bx - ax * bz;
        float cz = ax * by - ay * bx;
        float cns = cx * cx + cy * cy + cz * cz;
        float cn = sqrtf(cns);

        // pos prefetch for next tile
        {
            int jn = (jt < 23) ? (j0 + 16) : j0;
            const float* pn = pos + (size_t)(b * N_ + jn + ln) * 3;
            bx = pn[0]; by = pn[1]; bz = pn[2];
        }

        float var = Saa * dotv * dotv + Sbb * cns + Scc +
                    2.f * (Sab * dotv * cn + Sac * dotv + Sbc * cn);
        float rstd = rsqrtf(var + LN_EPS);
        f16 d2 = (f16)(dotv * rstd), c2 = (f16)(cn * rstd), r2 = (f16)rstd;
        f16x2 D2 = {d2, d2}, C2 = {c2, c2}, R2 = {r2, r2};
        const f16x2 Z = {(f16)0.f, (f16)0.f};

        // ---- B-fragments (relu_h) in registers; coeff from LDS per kc ----
        f16x8 bF[4];
#pragma unroll
        for (int kc = 0; kc < 4; ++kc) {
            uint4 cag = *(const uint4*)(cS + kc * 16 + h4 * 4);
            uint4 cbg = *(const uint4*)(cS + 64 + kc * 16 + h4 * 4);
            uint4 ccg = *(const uint4*)(cS + 128 + kc * 16 + h4 * 4);
            uint4 vb  = *(const uint4*)(cS + 192 + kc * 16 + h4 * 4);
            f16x2 vp0 = __builtin_elementwise_max(D2 * u2h(cag.x) + (C2 * u2h(cbg.x) + (R2 * u2h(ccg.x) + u2h(vb.x))), Z);
            f16x2 vp1 = __builtin_elementwise_max(D2 * u2h(cag.y) + (C2 * u2h(cbg.y) + (R2 * u2h(ccg.y) + u2h(vb.y))), Z);
            f16x2 vp2 = __builtin_elementwise_max(D2 * u2h(cag.z) + (C2 * u2h(cbg.z) + (R2 * u2h(ccg.z) + u2h(vb.z))), Z);
            f16x2 vp3 = __builtin_elementwise_max(D2 * u2h(cag.w) + (C2 * u2h(cbg.w) + (R2 * u2h(ccg.w) + u2h(vb.w))), Z);
            f16x4 q01 = __builtin_shufflevector(vp0, vp1, 0, 1, 2, 3);
            f16x4 q23 = __builtin_shufflevector(vp2, vp3, 0, 1, 2, 3);
            bF[kc] = __builtin_shufflevector(q01, q23, 0, 1, 2, 3, 4, 5, 6, 7);
        }

        // ---- acc init = ti ----
        f32x4v acc[8];
#pragma unroll
        for (int mf = 0; mf < 8; ++mf) {
            f16x2 t0 = u2h(tih[mf * 2]);
            f16x2 t1 = u2h(tih[mf * 2 + 1]);
            acc[mf][0] = (float)t0[0]; acc[mf][1] = (float)t0[1];
            acc[mf][2] = (float)t1[0]; acc[mf][3] = (float)t1[1];
        }

        // ---- GEMM: A from LDS, B in regs ----
#pragma unroll
        for (int kc = 0; kc < 4; ++kc) {
            const int kb = (kc * 64 + h4 * 16) ^ ((ln & 7) << 4);
#pragma unroll
            for (int mf = 0; mf < 8; ++mf) {
                f16x8 aFr = *(const f16x8*)(smem + (mf * 16 + ln) * 256 + kb);
                acc[mf] = __builtin_amdgcn_mfma_f32_16x16x32_f16(aFr, bF[kc], acc[mf], 0, 0, 0);
            }
        }

        // ---- phaseC: relu(acc+tj) dot sw; reduce over h4 ----
        unsigned int tju[16] = {tj0.x, tj0.y, tj0.z, tj0.w, tj1.x, tj1.y, tj1.z, tj1.w,
                                tj2.x, tj2.y, tj2.z, tj2.w, tj3.x, tj3.y, tj3.z, tj3.w};
        float part = 0.f;
#pragma unroll
        for (int mf = 0; mf < 8; ++mf) {
            f16x2 s0 = u2h(swR[mf].x), s1 = u2h(swR[mf].y);
            f16x2 jh0 = u2h(tju[mf * 2]), jh1 = u2h(tju[mf * 2 + 1]);
            part += fmaxf(acc[mf][0] + (float)jh0[0], 0.f) * (float)s0[0];
            part += fmaxf(acc[mf][1] + (float)jh0[1], 0.f) * (float)s0[1];
            part += fmaxf(acc[mf][2] + (float)jh1[0], 0.f) * (float)s1[0];
            part += fmaxf(acc[mf][3] + (float)jh1[1], 0.f) * (float)s1[1];
        }
        part += __shfl_xor(part, 16);
        part += __shfl_xor(part, 32);
        float sc = part + sb2v;
        if (h4 == 0) scoreRow[j0 + ln] = sc;

        // ---- online stats + flash accH accumulate (of relu_h = bF) ----
        float mn = fmaxf(m_run, sc);
        float sca = expf(m_run - mn);    // 0 on first tile, 1 when no update
        float a = expf(sc - mn);
        if (mn > m_run) {
#pragma unroll
            for (int kc = 0; kc < 4; ++kc)
#pragma unroll
                for (int e = 0; e < 8; ++e) accH[kc][e] *= sca;
        }
        s_run = s_run * sca + a;
        m_run = mn;
#pragma unroll
        for (int kc = 0; kc < 4; ++kc)
#pragma unroll
            for (int e = 0; e < 8; ++e)
                accH[kc][e] = fmaf(a, (float)bF[kc][e], accH[kc][e]);
    }

    // ---- epilogue: merge over ln bits — max first, single rescale, tree sums ----
    float m_tot = m_run;
#pragma unroll
    for (int d = 1; d < 16; d <<= 1) m_tot = fmaxf(m_tot, __shfl_xor(m_tot, d));
    float fsc = expf(m_run - m_tot);
    s_run *= fsc;
#pragma unroll
    for (int kc = 0; kc < 4; ++kc)
#pragma unroll
        for (int e = 0; e < 8; ++e) accH[kc][e] *= fsc;
#pragma unroll
    for (int d = 1; d < 16; d <<= 1) {
        s_run += __shfl_xor(s_run, d);
#pragma unroll
        for (int kc = 0; kc < 4; ++kc)
#pragma unroll
            for (int e = 0; e < 8; ++e) accH[kc][e] += __shfl_xor(accH[kc][e], d);
    }
    if (lane == 0) {
        rowmax[b * N_ + i] = m_tot;
        rowsum[b * N_ + i] = s_run;
    }

    // ---- accH @ vW2 (fp16, LDS): lane (ln,h4) dims d=kc*32+h4*8+e -> f=ln*4..+3 ----
    float xp0 = 0.f, xp1 = 0.f, xp2 = 0.f, xp3 = 0.f;
#pragma unroll
    for (int kc = 0; kc < 4; ++kc) {
#pragma unroll
        for (int e = 0; e < 8; ++e) {
            int dIdx = kc * 32 + h4 * 8 + e;
            float av = accH[kc][e];
            uint2 wv = *(const uint2*)(smem + VW2_OFF + dIdx * 128 + ln * 8);
            f16x2 w01 = u2h(wv.x), w23 = u2h(wv.y);
            xp0 = fmaf(av, (float)w01[0], xp0); xp1 = fmaf(av, (float)w01[1], xp1);
            xp2 = fmaf(av, (float)w23[0], xp2); xp3 = fmaf(av, (float)w23[1], xp3);
        }
    }
    xp0 += __shfl_xor(xp0, 16); xp0 += __shfl_xor(xp0, 32);
    xp1 += __shfl_xor(xp1, 16); xp1 += __shfl_xor(xp1, 32);
    xp2 += __shfl_xor(xp2, 16); xp2 += __shfl_xor(xp2, 32);
    xp3 += __shfl_xor(xp3, 16); xp3 += __shfl_xor(xp3, 32);
    if (h4 == 0) {
        float4 o = {xp0, xp1, xp2, xp3};
        *(float4*)(xpart + (size_t)(b * N_ + i) * F_ + ln * 4) = o;
    }
}

// -------------------- per-batch softmax reduce: rowscale_i = exp(rmax_i-gmax)/total ----------
__global__ void k_gred(const float* __restrict__ rowmax, const float* __restrict__ rowsum,
                       float* __restrict__ rowscale) {
    int b = blockIdx.x, tid = threadIdx.x;   // 512
    __shared__ float mred[512], sred[512];
    float m = (tid < N_) ? rowmax[b * N_ + tid] : -1e30f;
    float s = (tid < N_) ? rowsum[b * N_ + tid] : 0.f;
    mred[tid] = m;
    __syncthreads();
    for (int st = 256; st > 0; st >>= 1) {
        if (tid < st) mred[tid] = fmaxf(mred[tid], mred[tid + st]);
        __syncthreads();
    }
    float gm = mred[0];
    sred[tid] = s * expf(m - gm);
    __syncthreads();
    for (int st = 256; st > 0; st >>= 1) {
        if (tid < st) sred[tid] += sred[tid + st];
        __syncthreads();
    }
    float inv = 1.f / sred[0];
    if (tid < N_) rowscale[b * N_ + tid] = expf(m - gm) * inv;
}

// -------------------- k_xlite: att normalize + accI + final combine --------------------
// x = 0.5*(xpart*rowscale + s*vb2) + 0.25*(s*in_i + att@inp), s = rowsum*rowscale
__global__ __launch_bounds__(256) void k_xlite(
    const float* __restrict__ inp, const float* __restrict__ vb2,
    float* __restrict__ scoresAtt, const float* __restrict__ rowmax,
    const float* __restrict__ rowsum, const float* __restrict__ rowscale,
    const float* __restrict__ xpart, float* __restrict__ xout) {
    int i = blockIdx.x, b = blockIdx.y;
    int tid = threadIdx.x;
    __shared__ float aLds[N_];
    __shared__ float accIp[256];

    const float rmaxI = rowmax[b * N_ + i];
    const float rscaleI = rowscale[b * N_ + i];
    float* scoreRow = scoresAtt + (size_t)(b * N_ + i) * N_;

    {
        float sc = scoreRow[tid];
        float a = expf(sc - rmaxI) * rscaleI;
        scoreRow[tid] = a; aLds[tid] = a;
        if (tid < N_ - 256) {
            float sc2 = scoreRow[tid + 256];
            float a2 = expf(sc2 - rmaxI) * rscaleI;
            scoreRow[tid + 256] = a2; aLds[tid + 256] = a2;
        }
    }
    __syncthreads();

    int f = tid & 63, q = tid >> 6;
    float aI = 0.f;
    const float* inB = inp + (size_t)b * N_ * F_;
    for (int j = q * 96; j < q * 96 + 96; ++j)
        aI = fmaf(aLds[j], inB[j * F_ + f], aI);
    accIp[tid] = aI;
    __syncthreads();

    if (tid < F_) {
        float accI = accIp[tid] + accIp[64 + tid] + accIp[128 + tid] + accIp[192 + tid];
        float s = rowsum[b * N_ + i] * rscaleI;
        float xp = xpart[(size_t)(b * N_ + i) * F_ + tid] * rscaleI;
        float r = 0.5f * (xp + s * vb2[tid]) +
                  0.25f * (s * inB[(size_t)i * F_ + tid] + accI);
        xout[(size_t)(b * N_ + i) * F_ + tid] = r;
    }
}

// -------------------- launch --------------------

extern "C" void kernel_launch(void* const* d_in, const int* in_sizes, int n_in,
                              void* d_out, int out_size, void* d_ws, size_t ws_size,
                              hipStream_t stream) {
    const float* inp   = (const float*)d_in[0];
    const float* pos   = (const float*)d_in[1];
    const float* vW1   = (const float*)d_in[2];
    const float* vb1   = (const float*)d_in[3];
    const float* vg    = (const float*)d_in[4];
    const float* vbeta = (const float*)d_in[5];
    const float* vW2   = (const float*)d_in[6];
    const float* vb2   = (const float*)d_in[7];
    const float* sW1   = (const float*)d_in[8];
    const float* sb1   = (const float*)d_in[9];
    const float* sW2   = (const float*)d_in[10];
    const float* sb2   = (const float*)d_in[11];

    float* xout   = (float*)d_out;                 // B*N*F
    float* attout = xout + B_ * N_ * F_;           // B*N*N (scores -> att in place)

    unsigned short* W2hT   = (unsigned short*)d_ws;                  // 32KB fp16
    unsigned int*   coeffP = (unsigned int*)((char*)d_ws + 32768);   // 1KB packed f16x2
    float*          scal   = (float*)((char*)d_ws + 33792);          // 6 scalars (pad)
    unsigned int*   sw16   = (unsigned int*)((char*)d_ws + 34048);   // 64 uints (256B)
    unsigned int*   t16    = (unsigned int*)((char*)d_ws + 34304);   // B*N*64 uints (768KB)
    float* rowmax   = (float*)((char*)d_ws + 34304 + B_ * N_ * 64 * 4);
    float* rowsum   = rowmax + B_ * N_;
    float* rowscale = rowsum + B_ * N_;
    float* xpart    = rowscale + B_ * N_;          // B*N*64 fp32 (768KB)

    k_prep<<<B_ * N_ + 128 + 1, 128, 0, stream>>>(
        inp, sW1, vb2, sb1, vW2, vW1, vb1, vg, vbeta, sW2,
        t16, W2hT, coeffP, scal, sw16);
    k_scores<<<dim3(96, B_), 256, 0, stream>>>(
        pos, coeffP, scal, W2hT, vW2, t16, sw16, sb2, attout, rowmax, rowsum, xpart);
    k_gred<<<B_, 512, 0, stream>>>(rowmax, rowsum, rowscale);
    k_xlite<<<dim3(N_, B_), 256, 0, stream>>>(inp, vb2, attout, rowmax, rowsum,
                                              rowscale, xpart, xout);
}

// Round 17
// 157.634 us; speedup vs baseline: 4.9369x; 4.9369x over previous
//
#include <hip/hip_runtime.h>
#include <hip/hip_bf16.h>
#include <math.h>

#define B_ 8
#define N_ 384
#define F_ 64
#define H_ 128
#define LN_EPS 1e-5f

typedef _Float16 f16;
typedef f16 f16x2 __attribute__((ext_vector_type(2)));
typedef f16 f16x4 __attribute__((ext_vector_type(4)));
typedef f16 f16x8 __attribute__((ext_vector_type(8)));
typedef float f32x4v __attribute__((ext_vector_type(4)));

static __device__ __forceinline__ f16x2 u2h(unsigned int u) {
    union { unsigned int u; f16x2 h; } c; c.u = u; return c.h;
}
static __device__ __forceinline__ unsigned int h2u(f16 a, f16 b) {
    union { f16x2 h; unsigned int u; } c; c.h = (f16x2){a, b}; return c.u;
}

// packed-permuted index helpers: uint slot u = h4*16 + mf*2 + p packs
// elements (n, n+1) with n = mf*16 + h4*4 + 2p  (matches MFMA C/D row layout)
static __device__ __forceinline__ void perm_idx(int m, int& u, int& n0) {
    int h4 = (m >> 1) & 3, mf = m >> 3, p = m & 1;
    u = h4 * 16 + mf * 2 + p;
    n0 = mf * 16 + h4 * 4 + 2 * p;
}

// -------------------- fused setup kernel --------------------
__global__ __launch_bounds__(128) void k_prep(
    const float* __restrict__ inp, const float* __restrict__ sW1,
    const float* __restrict__ vb2, const float* __restrict__ sb1,
    const float* __restrict__ vW2, const float* __restrict__ vW1,
    const float* __restrict__ vb1, const float* __restrict__ vg,
    const float* __restrict__ vbeta, const float* __restrict__ sW2,
    unsigned int* __restrict__ t16, unsigned short* __restrict__ W2hT,
    unsigned int* __restrict__ coeffP, float* __restrict__ scal,
    unsigned int* __restrict__ sw16) {
    __shared__ float red[128];
    __shared__ float caS[128], cbS[128], ccS[128];
    const int bx = blockIdx.x;
    const int tid = threadIdx.x;

    if (bx < B_ * N_) {
        // tt[n] = 0.25*(in[row]+vb2)@sW1[:,n] + 0.5*sb1[n] ; pack-permute to t16
        int row = bx, n = tid;
        float acc = 0.f;
#pragma unroll
        for (int f = 0; f < F_; ++f)
            acc = fmaf(0.25f * (inp[row * F_ + f] + vb2[f]), sW1[f * H_ + n], acc);
        red[n] = acc + 0.5f * sb1[n];
        __syncthreads();
        if (tid < 64) {
            int u, n0; perm_idx(tid, u, n0);
            t16[row * 64 + u] = h2u((f16)red[n0], (f16)red[n0 + 1]);
        }
        return;
    }
    if (bx < B_ * N_ + 128) {
        int idx = (bx - B_ * N_) * 128 + tid;
        int k = idx >> 7, n = idx & 127;
        float acc = 0.f;
#pragma unroll
        for (int f = 0; f < F_; ++f) acc = fmaf(vW2[k * F_ + f], sW1[f * H_ + n], acc);
        f16 hv = (f16)(0.5f * acc);
        W2hT[n * H_ + k] = *reinterpret_cast<unsigned short*>(&hv);
        return;
    }

    // ---- algebraic-LN coefficients + sw16 ----
    const int d = tid;   // 128
    float a = vW1[d], bb = vW1[H_ + d], c = vb1[d];
    float mA, mB, mC, Saa, Sbb, Scc, Sab, Sac, Sbc;
    float ca, cb, cc;
#define BMEAN(OUT, VAL)                                                  \
    red[d] = (VAL); __syncthreads();                                     \
    for (int st = 64; st > 0; st >>= 1) {                                \
        if (d < st) red[d] += red[d + st];                               \
        __syncthreads();                                                 \
    }                                                                    \
    OUT = red[0] * (1.f / 128.f); __syncthreads();

    BMEAN(mA, a); BMEAN(mB, bb); BMEAN(mC, c);
    ca = a - mA; cb = bb - mB; cc = c - mC;
    caS[d] = ca * vg[d]; cbS[d] = cb * vg[d]; ccS[d] = cc * vg[d];
    BMEAN(Saa, ca * ca); BMEAN(Sbb, cb * cb); BMEAN(Scc, cc * cc);
    BMEAN(Sab, ca * cb); BMEAN(Sac, ca * cc); BMEAN(Sbc, cb * cc);
#undef BMEAN
    __syncthreads();
    if (d < 64) {
        int d0 = 2 * d;
        coeffP[d]       = h2u((f16)caS[d0], (f16)caS[d0 + 1]);
        coeffP[64 + d]  = h2u((f16)cbS[d0], (f16)cbS[d0 + 1]);
        coeffP[128 + d] = h2u((f16)ccS[d0], (f16)ccS[d0 + 1]);
        coeffP[192 + d] = h2u((f16)vbeta[d0], (f16)vbeta[d0 + 1]);
        int u, n0; perm_idx(d, u, n0);
        sw16[u] = h2u((f16)sW2[n0], (f16)sW2[n0 + 1]);
    }
    if (d == 0) {
        scal[0] = Saa; scal[1] = Sbb; scal[2] = Scc;
        scal[3] = Sab; scal[4] = Sac; scal[5] = Sbc;
    }
}

// -------------------- phase 1: scores + flash accH --------------------
// R16 body (coeff table in LDS => -64 persistent VGPR vs R15; vW2 fp16 => LDS 50KB)
// but NO min-waves launch-bound arg: 3x confirmed (R5/R6/R16) that a cap below the
// loop-carried state (accH fp32 etc.) forces catastrophic scratch spills (84 VGPR,
// 166MB WRITE). Natural allocation predicted 130-170 VGPR => 3 waves/SIMD if <=170.
#define VW2_OFF   32768
#define COEFF_OFF 49152
__global__ __launch_bounds__(256) void k_scores(
    const float* __restrict__ pos, const unsigned int* __restrict__ coeffP,
    const float* __restrict__ scal, const unsigned short* __restrict__ W2hT,
    const float* __restrict__ vW2, const unsigned int* __restrict__ t16,
    const unsigned int* __restrict__ sw16, const float* __restrict__ sb2,
    float* __restrict__ scores, float* __restrict__ rowmax,
    float* __restrict__ rowsum, float* __restrict__ xpart) {
    __shared__ __align__(16) char smem[50176];

    const int tid = threadIdx.x;
    const int b = blockIdx.y;
    const int w = tid >> 6, lane = tid & 63;
    const int i = blockIdx.x * 4 + w;
    const int ln = lane & 15, h4 = lane >> 4;

    // ---- one-time stage: W' swizzled + vW2 fp16 + coeff copy ----
#pragma unroll
    for (int s = 0; s < 8; ++s) {
        int idx = tid + s * 256;
        int n = idx >> 4, c = idx & 15;
        uint4 v = *(const uint4*)(W2hT + n * H_ + c * 8);
        *(uint4*)(smem + ((n * 256 + c * 16) ^ ((n & 7) << 4))) = v;
    }
#pragma unroll
    for (int s = 0; s < 16; ++s) {
        int idx = tid + s * 256;            // 0..4095 packed fp16 pairs of vW2 (128x64)
        float2 v = *(const float2*)((const float*)vW2 + idx * 2);
        *(unsigned int*)(smem + VW2_OFF + idx * 4) = h2u((f16)v.x, (f16)v.y);
    }
    ((unsigned int*)(smem + COEFF_OFF))[tid] = coeffP[tid];   // 256 uints
    __syncthreads();

    const unsigned int* cS = (const unsigned int*)(smem + COEFF_OFF);

    // ---- resident state (coeff reloads from LDS per tile) ----
    unsigned int tih[16];
    {
        const unsigned int* tiP = t16 + (size_t)(b * N_ + i) * 64 + h4 * 16;
#pragma unroll
        for (int s = 0; s < 4; ++s) {
            uint4 v = *(const uint4*)(tiP + s * 4);
            tih[s * 4 + 0] = v.x; tih[s * 4 + 1] = v.y;
            tih[s * 4 + 2] = v.z; tih[s * 4 + 3] = v.w;
        }
    }
    uint2 swR[8];
#pragma unroll
    for (int mf = 0; mf < 8; ++mf)
        swR[mf] = *(const uint2*)(sw16 + h4 * 16 + mf * 2);

    const float Saa = scal[0], Sbb = scal[1], Scc = scal[2];
    const float Sab = scal[3], Sac = scal[4], Sbc = scal[5];
    const float sb2v = sb2[0];

    const float* pi = pos + (size_t)(b * N_ + i) * 3;
    const float ax = pi[0], ay = pi[1], az = pi[2];
    float* scoreRow = scores + (size_t)(b * N_ + i) * N_;

    float m_run = -1e30f, s_run = 0.f;
    float accH[4][8];
#pragma unroll
    for (int kc = 0; kc < 4; ++kc)
#pragma unroll
        for (int e = 0; e < 8; ++e) accH[kc][e] = 0.f;

    // pos prefetch for tile 0
    const float* pj0p = pos + (size_t)(b * N_ + ln) * 3;
    float bx = pj0p[0], by = pj0p[1], bz = pj0p[2];

#pragma unroll 1
    for (int jt = 0; jt < 24; ++jt) {
        const int j0 = jt * 16;

        // ---- tj prefetch (packed), consumed at phaseC ----
        const unsigned int* tjP = t16 + (size_t)(b * N_ + j0 + ln) * 64 + h4 * 16;
        uint4 tj0 = *(const uint4*)(tjP);
        uint4 tj1 = *(const uint4*)(tjP + 4);
        uint4 tj2 = *(const uint4*)(tjP + 8);
        uint4 tj3 = *(const uint4*)(tjP + 12);

        // ---- geometry ----
        float dotv = ax * bx + ay * by + az * bz;
        float cx = ay * bz - az * by;
        float cy = az * bx - ax * bz;
        float cz = ax * by - ay * bx;
        float cns = cx * cx + cy * cy + cz * cz;
        float cn = sqrtf(cns);

        // pos prefetch for next tile
        {
            int jn = (jt < 23) ? (j0 + 16) : j0;
            const float* pn = pos + (size_t)(b * N_ + jn + ln) * 3;
            bx = pn[0]; by = pn[1]; bz = pn[2];
        }

        float var = Saa * dotv * dotv + Sbb * cns + Scc +
                    2.f * (Sab * dotv * cn + Sac * dotv + Sbc * cn);
        float rstd = rsqrtf(var + LN_EPS);
        f16 d2 = (f16)(dotv * rstd), c2 = (f16)(cn * rstd), r2 = (f16)rstd;
        f16x2 D2 = {d2, d2}, C2 = {c2, c2}, R2 = {r2, r2};
        const f16x2 Z = {(f16)0.f, (f16)0.f};

        // ---- B-fragments (relu_h) in registers; coeff from LDS per kc ----
        f16x8 bF[4];
#pragma unroll
        for (int kc = 0; kc < 4; ++kc) {
            uint4 cag = *(const uint4*)(cS + kc * 16 + h4 * 4);
            uint4 cbg = *(const uint4*)(cS + 64 + kc * 16 + h4 * 4);
            uint4 ccg = *(const uint4*)(cS + 128 + kc * 16 + h4 * 4);
            uint4 vb  = *(const uint4*)(cS + 192 + kc * 16 + h4 * 4);
            f16x2 vp0 = __builtin_elementwise_max(D2 * u2h(cag.x) + (C2 * u2h(cbg.x) + (R2 * u2h(ccg.x) + u2h(vb.x))), Z);
            f16x2 vp1 = __builtin_elementwise_max(D2 * u2h(cag.y) + (C2 * u2h(cbg.y) + (R2 * u2h(ccg.y) + u2h(vb.y))), Z);
            f16x2 vp2 = __builtin_elementwise_max(D2 * u2h(cag.z) + (C2 * u2h(cbg.z) + (R2 * u2h(ccg.z) + u2h(vb.z))), Z);
            f16x2 vp3 = __builtin_elementwise_max(D2 * u2h(cag.w) + (C2 * u2h(cbg.w) + (R2 * u2h(ccg.w) + u2h(vb.w))), Z);
            f16x4 q01 = __builtin_shufflevector(vp0, vp1, 0, 1, 2, 3);
            f16x4 q23 = __builtin_shufflevector(vp2, vp3, 0, 1, 2, 3);
            bF[kc] = __builtin_shufflevector(q01, q23, 0, 1, 2, 3, 4, 5, 6, 7);
        }

        // ---- acc init = ti ----
        f32x4v acc[8];
#pragma unroll
        for (int mf = 0; mf < 8; ++mf) {
            f16x2 t0 = u2h(tih[mf * 2]);
            f16x2 t1 = u2h(tih[mf * 2 + 1]);
            acc[mf][0] = (float)t0[0]; acc[mf][1] = (float)t0[1];
            acc[mf][2] = (float)t1[0]; acc[mf][3] = (float)t1[1];
        }

        // ---- GEMM: A from LDS, B in regs ----
#pragma unroll
        for (int kc = 0; kc < 4; ++kc) {
            const int kb = (kc * 64 + h4 * 16) ^ ((ln & 7) << 4);
#pragma unroll
            for (int mf = 0; mf < 8; ++mf) {
                f16x8 aFr = *(const f16x8*)(smem + (mf * 16 + ln) * 256 + kb);
                acc[mf] = __builtin_amdgcn_mfma_f32_16x16x32_f16(aFr, bF[kc], acc[mf], 0, 0, 0);
            }
        }

        // ---- phaseC: relu(acc+tj) dot sw; reduce over h4 ----
        unsigned int tju[16] = {tj0.x, tj0.y, tj0.z, tj0.w, tj1.x, tj1.y, tj1.z, tj1.w,
                                tj2.x, tj2.y, tj2.z, tj2.w, tj3.x, tj3.y, tj3.z, tj3.w};
        float part = 0.f;
#pragma unroll
        for (int mf = 0; mf < 8; ++mf) {
            f16x2 s0 = u2h(swR[mf].x), s1 = u2h(swR[mf].y);
            f16x2 jh0 = u2h(tju[mf * 2]), jh1 = u2h(tju[mf * 2 + 1]);
            part += fmaxf(acc[mf][0] + (float)jh0[0], 0.f) * (float)s0[0];
            part += fmaxf(acc[mf][1] + (float)jh0[1], 0.f) * (float)s0[1];
            part += fmaxf(acc[mf][2] + (float)jh1[0], 0.f) * (float)s1[0];
            part += fmaxf(acc[mf][3] + (float)jh1[1], 0.f) * (float)s1[1];
        }
        part += __shfl_xor(part, 16);
        part += __shfl_xor(part, 32);
        float sc = part + sb2v;
        if (h4 == 0) scoreRow[j0 + ln] = sc;

        // ---- online stats + flash accH accumulate (of relu_h = bF) ----
        float mn = fmaxf(m_run, sc);
        float sca = expf(m_run - mn);    // 0 on first tile, 1 when no update
        float a = expf(sc - mn);
        if (mn > m_run) {
#pragma unroll
            for (int kc = 0; kc < 4; ++kc)
#pragma unroll
                for (int e = 0; e < 8; ++e) accH[kc][e] *= sca;
        }
        s_run = s_run * sca + a;
        m_run = mn;
#pragma unroll
        for (int kc = 0; kc < 4; ++kc)
#pragma unroll
            for (int e = 0; e < 8; ++e)
                accH[kc][e] = fmaf(a, (float)bF[kc][e], accH[kc][e]);
    }

    // ---- epilogue: merge over ln bits — max first, single rescale, tree sums ----
    float m_tot = m_run;
#pragma unroll
    for (int d = 1; d < 16; d <<= 1) m_tot = fmaxf(m_tot, __shfl_xor(m_tot, d));
    float fsc = expf(m_run - m_tot);
    s_run *= fsc;
#pragma unroll
    for (int kc = 0; kc < 4; ++kc)
#pragma unroll
        for (int e = 0; e < 8; ++e) accH[kc][e] *= fsc;
#pragma unroll
    for (int d = 1; d < 16; d <<= 1) {
        s_run += __shfl_xor(s_run, d);
#pragma unroll
        for (int kc = 0; kc < 4; ++kc)
#pragma unroll
            for (int e = 0; e < 8; ++e) accH[kc][e] += __shfl_xor(accH[kc][e], d);
    }
    if (lane == 0) {
        rowmax[b * N_ + i] = m_tot;
        rowsum[b * N_ + i] = s_run;
    }

    // ---- accH @ vW2 (fp16, LDS): lane (ln,h4) dims d=kc*32+h4*8+e -> f=ln*4..+3 ----
    float xp0 = 0.f, xp1 = 0.f, xp2 = 0.f, xp3 = 0.f;
#pragma unroll
    for (int kc = 0; kc < 4; ++kc) {
#pragma unroll
        for (int e = 0; e < 8; ++e) {
            int dIdx = kc * 32 + h4 * 8 + e;
            float av = accH[kc][e];
            uint2 wv = *(const uint2*)(smem + VW2_OFF + dIdx * 128 + ln * 8);
            f16x2 w01 = u2h(wv.x), w23 = u2h(wv.y);
            xp0 = fmaf(av, (float)w01[0], xp0); xp1 = fmaf(av, (float)w01[1], xp1);
            xp2 = fmaf(av, (float)w23[0], xp2); xp3 = fmaf(av, (float)w23[1], xp3);
        }
    }
    xp0 += __shfl_xor(xp0, 16); xp0 += __shfl_xor(xp0, 32);
    xp1 += __shfl_xor(xp1, 16); xp1 += __shfl_xor(xp1, 32);
    xp2 += __shfl_xor(xp2, 16); xp2 += __shfl_xor(xp2, 32);
    xp3 += __shfl_xor(xp3, 16); xp3 += __shfl_xor(xp3, 32);
    if (h4 == 0) {
        float4 o = {xp0, xp1, xp2, xp3};
        *(float4*)(xpart + (size_t)(b * N_ + i) * F_ + ln * 4) = o;
    }
}

// -------------------- per-batch softmax reduce: rowscale_i = exp(rmax_i-gmax)/total ----------
__global__ void k_gred(const float* __restrict__ rowmax, const float* __restrict__ rowsum,
                       float* __restrict__ rowscale) {
    int b = blockIdx.x, tid = threadIdx.x;   // 512
    __shared__ float mred[512], sred[512];
    float m = (tid < N_) ? rowmax[b * N_ + tid] : -1e30f;
    float s = (tid < N_) ? rowsum[b * N_ + tid] : 0.f;
    mred[tid] = m;
    __syncthreads();
    for (int st = 256; st > 0; st >>= 1) {
        if (tid < st) mred[tid] = fmaxf(mred[tid], mred[tid + st]);
        __syncthreads();
    }
    float gm = mred[0];
    sred[tid] = s * expf(m - gm);
    __syncthreads();
    for (int st = 256; st > 0; st >>= 1) {
        if (tid < st) sred[tid] += sred[tid + st];
        __syncthreads();
    }
    float inv = 1.f / sred[0];
    if (tid < N_) rowscale[b * N_ + tid] = expf(m - gm) * inv;
}

// -------------------- k_xlite: att normalize + accI + final combine --------------------
// x = 0.5*(xpart*rowscale + s*vb2) + 0.25*(s*in_i + att@inp), s = rowsum*rowscale
__global__ __launch_bounds__(256) void k_xlite(
    const float* __restrict__ inp, const float* __restrict__ vb2,
    float* __restrict__ scoresAtt, const float* __restrict__ rowmax,
    const float* __restrict__ rowsum, const float* __restrict__ rowscale,
    const float* __restrict__ xpart, float* __restrict__ xout) {
    int i = blockIdx.x, b = blockIdx.y;
    int tid = threadIdx.x;
    __shared__ float aLds[N_];
    __shared__ float accIp[256];

    const float rmaxI = rowmax[b * N_ + i];
    const float rscaleI = rowscale[b * N_ + i];
    float* scoreRow = scoresAtt + (size_t)(b * N_ + i) * N_;

    {
        float sc = scoreRow[tid];
        float a = expf(sc - rmaxI) * rscaleI;
        scoreRow[tid] = a; aLds[tid] = a;
        if (tid < N_ - 256) {
            float sc2 = scoreRow[tid + 256];
            float a2 = expf(sc2 - rmaxI) * rscaleI;
            scoreRow[tid + 256] = a2; aLds[tid + 256] = a2;
        }
    }
    __syncthreads();

    int f = tid & 63, q = tid >> 6;
    float aI = 0.f;
    const float* inB = inp + (size_t)b * N_ * F_;
    for (int j = q * 96; j < q * 96 + 96; ++j)
        aI = fmaf(aLds[j], inB[j * F_ + f], aI);
    accIp[tid] = aI;
    __syncthreads();

    if (tid < F_) {
        float accI = accIp[tid] + accIp[64 + tid] + accIp[128 + tid] + accIp[192 + tid];
        float s = rowsum[b * N_ + i] * rscaleI;
        float xp = xpart[(size_t)(b * N_ + i) * F_ + tid] * rscaleI;
        float r = 0.5f * (xp + s * vb2[tid]) +
                  0.25f * (s * inB[(size_t)i * F_ + tid] + accI);
        xout[(size_t)(b * N_ + i) * F_ + tid] = r;
    }
}

// -------------------- launch --------------------

extern "C" void kernel_launch(void* const* d_in, const int* in_sizes, int n_in,
                              void* d_out, int out_size, void* d_ws, size_t ws_size,
                              hipStream_t stream) {
    const float* inp   = (const float*)d_in[0];
    const float* pos   = (const float*)d_in[1];
    const float* vW1   = (const float*)d_in[2];
    const float* vb1   = (const float*)d_in[3];
    const float* vg    = (const float*)d_in[4];
    const float* vbeta = (const float*)d_in[5];
    const float* vW2   = (const float*)d_in[6];
    const float* vb2   = (const float*)d_in[7];
    const float* sW1   = (const float*)d_in[8];
    const float* sb1   = (const float*)d_in[9];
    const float* sW2   = (const float*)d_in[10];
    const float* sb2   = (const float*)d_in[11];

    float* xout   = (float*)d_out;                 // B*N*F
    float* attout = xout + B_ * N_ * F_;           // B*N*N (scores -> att in place)

    unsigned short* W2hT   = (unsigned short*)d_ws;                  // 32KB fp16
    unsigned int*   coeffP = (unsigned int*)((char*)d_ws + 32768);   // 1KB packed f16x2
    float*          scal   = (float*)((char*)d_ws + 33792);          // 6 scalars (pad)
    unsigned int*   sw16   = (unsigned int*)((char*)d_ws + 34048);   // 64 uints (256B)
    unsigned int*   t16    = (unsigned int*)((char*)d_ws + 34304);   // B*N*64 uints (768KB)
    float* rowmax   = (float*)((char*)d_ws + 34304 + B_ * N_ * 64 * 4);
    float* rowsum   = rowmax + B_ * N_;
    float* rowscale = rowsum + B_ * N_;
    float* xpart    = rowscale + B_ * N_;          // B*N*64 fp32 (768KB)

    k_prep<<<B_ * N_ + 128 + 1, 128, 0, stream>>>(
        inp, sW1, vb2, sb1, vW2, vW1, vb1, vg, vbeta, sW2,
        t16, W2hT, coeffP, scal, sw16);
    k_scores<<<dim3(96, B_), 256, 0, stream>>>(
        pos, coeffP, scal, W2hT, vW2, t16, sw16, sb2, attout, rowmax, rowsum, xpart);
    k_gred<<<B_, 512, 0, stream>>>(rowmax, rowsum, rowscale);
    k_xlite<<<dim3(N_, B_), 256, 0, stream>>>(inp, vb2, attout, rowmax, rowsum,
                                              rowscale, xpart, xout);
}

// Round 18
// 144.083 us; speedup vs baseline: 5.4012x; 1.0940x over previous
//
#include <hip/hip_runtime.h>
#include <hip/hip_bf16.h>
#include <math.h>

#define B_ 8
#define N_ 384
#define F_ 64
#define H_ 128
#define LN_EPS 1e-5f

typedef _Float16 f16;
typedef f16 f16x2 __attribute__((ext_vector_type(2)));
typedef f16 f16x4 __attribute__((ext_vector_type(4)));
typedef f16 f16x8 __attribute__((ext_vector_type(8)));
typedef float f32x4v __attribute__((ext_vector_type(4)));

static __device__ __forceinline__ f16x2 u2h(unsigned int u) {
    union { unsigned int u; f16x2 h; } c; c.u = u; return c.h;
}
static __device__ __forceinline__ unsigned int h2u(f16 a, f16 b) {
    union { f16x2 h; unsigned int u; } c; c.h = (f16x2){a, b}; return c.u;
}

// packed-permuted index helpers: uint slot u = h4*16 + mf*2 + p packs
// elements (n, n+1) with n = mf*16 + h4*4 + 2p  (matches MFMA C/D row layout)
static __device__ __forceinline__ void perm_idx(int m, int& u, int& n0) {
    int h4 = (m >> 1) & 3, mf = m >> 3, p = m & 1;
    u = h4 * 16 + mf * 2 + p;
    n0 = mf * 16 + h4 * 4 + 2 * p;
}

// -------------------- fused setup kernel --------------------
__global__ __launch_bounds__(128) void k_prep(
    const float* __restrict__ inp, const float* __restrict__ sW1,
    const float* __restrict__ vb2, const float* __restrict__ sb1,
    const float* __restrict__ vW2, const float* __restrict__ vW1,
    const float* __restrict__ vb1, const float* __restrict__ vg,
    const float* __restrict__ vbeta, const float* __restrict__ sW2,
    unsigned int* __restrict__ t16, unsigned short* __restrict__ W2hT,
    unsigned int* __restrict__ coeffP, float* __restrict__ scal,
    unsigned int* __restrict__ sw16) {
    __shared__ float red[128];
    __shared__ float caS[128], cbS[128], ccS[128];
    const int bx = blockIdx.x;
    const int tid = threadIdx.x;

    if (bx < B_ * N_) {
        // tt[n] = 0.25*(in[row]+vb2)@sW1[:,n] + 0.5*sb1[n] ; pack-permute to t16
        int row = bx, n = tid;
        float acc = 0.f;
#pragma unroll
        for (int f = 0; f < F_; ++f)
            acc = fmaf(0.25f * (inp[row * F_ + f] + vb2[f]), sW1[f * H_ + n], acc);
        red[n] = acc + 0.5f * sb1[n];
        __syncthreads();
        if (tid < 64) {
            int u, n0; perm_idx(tid, u, n0);
            t16[row * 64 + u] = h2u((f16)red[n0], (f16)red[n0 + 1]);
        }
        return;
    }
    if (bx < B_ * N_ + 128) {
        int idx = (bx - B_ * N_) * 128 + tid;
        int k = idx >> 7, n = idx & 127;
        float acc = 0.f;
#pragma unroll
        for (int f = 0; f < F_; ++f) acc = fmaf(vW2[k * F_ + f], sW1[f * H_ + n], acc);
        f16 hv = (f16)(0.5f * acc);
        W2hT[n * H_ + k] = *reinterpret_cast<unsigned short*>(&hv);
        return;
    }

    // ---- algebraic-LN coefficients + sw16 ----
    const int d = tid;   // 128
    float a = vW1[d], bb = vW1[H_ + d], c = vb1[d];
    float mA, mB, mC, Saa, Sbb, Scc, Sab, Sac, Sbc;
    float ca, cb, cc;
#define BMEAN(OUT, VAL)                                                  \
    red[d] = (VAL); __syncthreads();                                     \
    for (int st = 64; st > 0; st >>= 1) {                                \
        if (d < st) red[d] += red[d + st];                               \
        __syncthreads();                                                 \
    }                                                                    \
    OUT = red[0] * (1.f / 128.f); __syncthreads();

    BMEAN(mA, a); BMEAN(mB, bb); BMEAN(mC, c);
    ca = a - mA; cb = bb - mB; cc = c - mC;
    caS[d] = ca * vg[d]; cbS[d] = cb * vg[d]; ccS[d] = cc * vg[d];
    BMEAN(Saa, ca * ca); BMEAN(Sbb, cb * cb); BMEAN(Scc, cc * cc);
    BMEAN(Sab, ca * cb); BMEAN(Sac, ca * cc); BMEAN(Sbc, cb * cc);
#undef BMEAN
    __syncthreads();
    if (d < 64) {
        int d0 = 2 * d;
        coeffP[d]       = h2u((f16)caS[d0], (f16)caS[d0 + 1]);
        coeffP[64 + d]  = h2u((f16)cbS[d0], (f16)cbS[d0 + 1]);
        coeffP[128 + d] = h2u((f16)ccS[d0], (f16)ccS[d0 + 1]);
        coeffP[192 + d] = h2u((f16)vbeta[d0], (f16)vbeta[d0 + 1]);
        int u, n0; perm_idx(d, u, n0);
        sw16[u] = h2u((f16)sW2[n0], (f16)sW2[n0 + 1]);
    }
    if (d == 0) {
        scal[0] = Saa; scal[1] = Sbb; scal[2] = Scc;
        scal[3] = Sab; scal[4] = Sac; scal[5] = Sbc;
    }
}

// -------------------- phase 1: scores + flash accH (R15 base + bF software pipeline) ----
// R15 config (coeff resident, vW2 fp32 LDS, no launch-bound cap — R5/R6/R16: a min-waves
// arg below loop-carried state spills catastrophically). NEW: 2-stage bF pipeline —
// construct tile t+1's B-fragments (VALU, independent) BETWEEN GEMM(t) and phaseC(t),
// hiding the MFMA drain that the in-order wave otherwise stalls on. +16 VGPR (bF_nxt).
#define VW2_OFF 32768
__global__ __launch_bounds__(256) void k_scores(
    const float* __restrict__ pos, const unsigned int* __restrict__ coeffP,
    const float* __restrict__ scal, const unsigned short* __restrict__ W2hT,
    const float* __restrict__ vW2, const unsigned int* __restrict__ t16,
    const unsigned int* __restrict__ sw16, const float* __restrict__ sb2,
    float* __restrict__ scores, float* __restrict__ rowmax,
    float* __restrict__ rowsum, float* __restrict__ xpart) {
    __shared__ __align__(16) char smem[65536];   // 32KB W' (swizzled) + 32KB vW2 fp32

    const int tid = threadIdx.x;
    const int b = blockIdx.y;
    const int w = tid >> 6, lane = tid & 63;
    const int i = blockIdx.x * 4 + w;
    const int ln = lane & 15, h4 = lane >> 4;

    // ---- one-time stage: W' swizzled + vW2 fp32 ----
#pragma unroll
    for (int s = 0; s < 8; ++s) {
        int idx = tid + s * 256;
        int n = idx >> 4, c = idx & 15;
        uint4 v = *(const uint4*)(W2hT + n * H_ + c * 8);
        *(uint4*)(smem + ((n * 256 + c * 16) ^ ((n & 7) << 4))) = v;
    }
#pragma unroll
    for (int s = 0; s < 8; ++s) {
        int idx = tid + s * 256;            // 0..2047 float4 chunks of vW2 (128x64)
        uint4 v = *(const uint4*)((const float*)vW2 + idx * 4);
        *(uint4*)(smem + VW2_OFF + idx * 16) = v;
    }
    __syncthreads();

    // ---- resident state ----
    uint4 cagR[4], cbgR[4], ccgR[4], vbR[4];
#pragma unroll
    for (int kc = 0; kc < 4; ++kc) {
        cagR[kc] = *(const uint4*)(coeffP + kc * 16 + h4 * 4);
        cbgR[kc] = *(const uint4*)(coeffP + 64 + kc * 16 + h4 * 4);
        ccgR[kc] = *(const uint4*)(coeffP + 128 + kc * 16 + h4 * 4);
        vbR[kc]  = *(const uint4*)(coeffP + 192 + kc * 16 + h4 * 4);
    }
    unsigned int tih[16];
    {
        const unsigned int* tiP = t16 + (size_t)(b * N_ + i) * 64 + h4 * 16;
#pragma unroll
        for (int s = 0; s < 4; ++s) {
            uint4 v = *(const uint4*)(tiP + s * 4);
            tih[s * 4 + 0] = v.x; tih[s * 4 + 1] = v.y;
            tih[s * 4 + 2] = v.z; tih[s * 4 + 3] = v.w;
        }
    }
    uint2 swR[8];
#pragma unroll
    for (int mf = 0; mf < 8; ++mf)
        swR[mf] = *(const uint2*)(sw16 + h4 * 16 + mf * 2);

    const float Saa = scal[0], Sbb = scal[1], Scc = scal[2];
    const float Sab = scal[3], Sac = scal[4], Sbc = scal[5];
    const float sb2v = sb2[0];

    const float* pi = pos + (size_t)(b * N_ + i) * 3;
    const float ax = pi[0], ay = pi[1], az = pi[2];
    float* scoreRow = scores + (size_t)(b * N_ + i) * N_;

    float m_run = -1e30f, s_run = 0.f;
    float accH[4][8];
#pragma unroll
    for (int kc = 0; kc < 4; ++kc)
#pragma unroll
        for (int e = 0; e < 8; ++e) accH[kc][e] = 0.f;

    // bF construction from a given j-pos (uses resident coeffs)
    auto makeBF = [&](float bx, float by, float bz, f16x8 (&bF)[4]) {
        float dotv = ax * bx + ay * by + az * bz;
        float cx = ay * bz - az * by;
        float cy = az * bx - ax * bz;
        float cz = ax * by - ay * bx;
        float cns = cx * cx + cy * cy + cz * cz;
        float cn = sqrtf(cns);
        float var = Saa * dotv * dotv + Sbb * cns + Scc +
                    2.f * (Sab * dotv * cn + Sac * dotv + Sbc * cn);
        float rstd = rsqrtf(var + LN_EPS);
        f16 d2 = (f16)(dotv * rstd), c2 = (f16)(cn * rstd), r2 = (f16)rstd;
        f16x2 D2 = {d2, d2}, C2 = {c2, c2}, R2 = {r2, r2};
        const f16x2 Z = {(f16)0.f, (f16)0.f};
#pragma unroll
        for (int kc = 0; kc < 4; ++kc) {
            f16x2 vp0 = __builtin_elementwise_max(D2 * u2h(cagR[kc].x) + (C2 * u2h(cbgR[kc].x) + (R2 * u2h(ccgR[kc].x) + u2h(vbR[kc].x))), Z);
            f16x2 vp1 = __builtin_elementwise_max(D2 * u2h(cagR[kc].y) + (C2 * u2h(cbgR[kc].y) + (R2 * u2h(ccgR[kc].y) + u2h(vbR[kc].y))), Z);
            f16x2 vp2 = __builtin_elementwise_max(D2 * u2h(cagR[kc].z) + (C2 * u2h(cbgR[kc].z) + (R2 * u2h(ccgR[kc].z) + u2h(vbR[kc].z))), Z);
            f16x2 vp3 = __builtin_elementwise_max(D2 * u2h(cagR[kc].w) + (C2 * u2h(cbgR[kc].w) + (R2 * u2h(ccgR[kc].w) + u2h(vbR[kc].w))), Z);
            f16x4 q01 = __builtin_shufflevector(vp0, vp1, 0, 1, 2, 3);
            f16x4 q23 = __builtin_shufflevector(vp2, vp3, 0, 1, 2, 3);
            bF[kc] = __builtin_shufflevector(q01, q23, 0, 1, 2, 3, 4, 5, 6, 7);
        }
    };

    // ---- prologue: bF for tile 0; pos prefetch for tile 1 ----
    f16x8 bF_cur[4], bF_nxt[4];
    float bx, by, bz;
    {
        const float* p0 = pos + (size_t)(b * N_ + ln) * 3;
        bx = p0[0]; by = p0[1]; bz = p0[2];
    }
    makeBF(bx, by, bz, bF_cur);
    {
        const float* p1 = pos + (size_t)(b * N_ + 16 + ln) * 3;
        bx = p1[0]; by = p1[1]; bz = p1[2];
    }

#pragma unroll 1
    for (int jt = 0; jt < 24; ++jt) {
        const int j0 = jt * 16;

        // ---- tj prefetch (packed), consumed at phaseC ----
        const unsigned int* tjP = t16 + (size_t)(b * N_ + j0 + ln) * 64 + h4 * 16;
        uint4 tj0 = *(const uint4*)(tjP);
        uint4 tj1 = *(const uint4*)(tjP + 4);
        uint4 tj2 = *(const uint4*)(tjP + 8);
        uint4 tj3 = *(const uint4*)(tjP + 12);

        // ---- acc init = ti ----
        f32x4v acc[8];
#pragma unroll
        for (int mf = 0; mf < 8; ++mf) {
            f16x2 t0 = u2h(tih[mf * 2]);
            f16x2 t1 = u2h(tih[mf * 2 + 1]);
            acc[mf][0] = (float)t0[0]; acc[mf][1] = (float)t0[1];
            acc[mf][2] = (float)t1[0]; acc[mf][3] = (float)t1[1];
        }

        // ---- GEMM: A from LDS, B = bF_cur ----
#pragma unroll
        for (int kc = 0; kc < 4; ++kc) {
            const int kb = (kc * 64 + h4 * 16) ^ ((ln & 7) << 4);
#pragma unroll
            for (int mf = 0; mf < 8; ++mf) {
                f16x8 aFr = *(const f16x8*)(smem + (mf * 16 + ln) * 256 + kb);
                acc[mf] = __builtin_amdgcn_mfma_f32_16x16x32_f16(aFr, bF_cur[kc], acc[mf], 0, 0, 0);
            }
        }

        // ---- construct NEXT tile's bF while MFMAs drain (independent VALU) ----
        {
            float gx = bx, gy = by, gz = bz;
            int jn2 = (jt + 2 < 24) ? (jt + 2) : 23;
            const float* pn = pos + (size_t)(b * N_ + jn2 * 16 + ln) * 3;
            bx = pn[0]; by = pn[1]; bz = pn[2];
            makeBF(gx, gy, gz, bF_nxt);
        }

        // ---- phaseC: relu(acc+tj) dot sw; reduce over h4 ----
        unsigned int tju[16] = {tj0.x, tj0.y, tj0.z, tj0.w, tj1.x, tj1.y, tj1.z, tj1.w,
                                tj2.x, tj2.y, tj2.z, tj2.w, tj3.x, tj3.y, tj3.z, tj3.w};
        float part = 0.f;
#pragma unroll
        for (int mf = 0; mf < 8; ++mf) {
            f16x2 s0 = u2h(swR[mf].x), s1 = u2h(swR[mf].y);
            f16x2 jh0 = u2h(tju[mf * 2]), jh1 = u2h(tju[mf * 2 + 1]);
            part += fmaxf(acc[mf][0] + (float)jh0[0], 0.f) * (float)s0[0];
            part += fmaxf(acc[mf][1] + (float)jh0[1], 0.f) * (float)s0[1];
            part += fmaxf(acc[mf][2] + (float)jh1[0], 0.f) * (float)s1[0];
            part += fmaxf(acc[mf][3] + (float)jh1[1], 0.f) * (float)s1[1];
        }
        part += __shfl_xor(part, 16);
        part += __shfl_xor(part, 32);
        float sc = part + sb2v;
        if (h4 == 0) scoreRow[j0 + ln] = sc;

        // ---- online stats + flash accH accumulate (of relu_h = bF_cur) ----
        float mn = fmaxf(m_run, sc);
        float sca = expf(m_run - mn);    // 0 on first tile, 1 when no update
        float a = expf(sc - mn);
        if (mn > m_run) {
#pragma unroll
            for (int kc = 0; kc < 4; ++kc)
#pragma unroll
                for (int e = 0; e < 8; ++e) accH[kc][e] *= sca;
        }
        s_run = s_run * sca + a;
        m_run = mn;
#pragma unroll
        for (int kc = 0; kc < 4; ++kc)
#pragma unroll
            for (int e = 0; e < 8; ++e)
                accH[kc][e] = fmaf(a, (float)bF_cur[kc][e], accH[kc][e]);

        // ---- rotate pipeline ----
#pragma unroll
        for (int kc = 0; kc < 4; ++kc) bF_cur[kc] = bF_nxt[kc];
    }

    // ---- epilogue: merge over ln bits — max first, single rescale, tree sums ----
    float m_tot = m_run;
#pragma unroll
    for (int d = 1; d < 16; d <<= 1) m_tot = fmaxf(m_tot, __shfl_xor(m_tot, d));
    float fsc = expf(m_run - m_tot);
    s_run *= fsc;
#pragma unroll
    for (int kc = 0; kc < 4; ++kc)
#pragma unroll
        for (int e = 0; e < 8; ++e) accH[kc][e] *= fsc;
#pragma unroll
    for (int d = 1; d < 16; d <<= 1) {
        s_run += __shfl_xor(s_run, d);
#pragma unroll
        for (int kc = 0; kc < 4; ++kc)
#pragma unroll
            for (int e = 0; e < 8; ++e) accH[kc][e] += __shfl_xor(accH[kc][e], d);
    }
    if (lane == 0) {
        rowmax[b * N_ + i] = m_tot;
        rowsum[b * N_ + i] = s_run;
    }

    // ---- accH @ vW2 (fp32, LDS): lane (ln,h4) dims d=kc*32+h4*8+e -> f=ln*4..+3 ----
    float xp0 = 0.f, xp1 = 0.f, xp2 = 0.f, xp3 = 0.f;
#pragma unroll
    for (int kc = 0; kc < 4; ++kc) {
#pragma unroll
        for (int e = 0; e < 8; ++e) {
            int dIdx = kc * 32 + h4 * 8 + e;
            float av = accH[kc][e];
            float4 wv = *(const float4*)(smem + VW2_OFF + dIdx * 256 + ln * 16);
            xp0 = fmaf(av, wv.x, xp0); xp1 = fmaf(av, wv.y, xp1);
            xp2 = fmaf(av, wv.z, xp2); xp3 = fmaf(av, wv.w, xp3);
        }
    }
    xp0 += __shfl_xor(xp0, 16); xp0 += __shfl_xor(xp0, 32);
    xp1 += __shfl_xor(xp1, 16); xp1 += __shfl_xor(xp1, 32);
    xp2 += __shfl_xor(xp2, 16); xp2 += __shfl_xor(xp2, 32);
    xp3 += __shfl_xor(xp3, 16); xp3 += __shfl_xor(xp3, 32);
    if (h4 == 0) {
        float4 o = {xp0, xp1, xp2, xp3};
        *(float4*)(xpart + (size_t)(b * N_ + i) * F_ + ln * 4) = o;
    }
}

// -------------------- per-batch softmax reduce: rowscale_i = exp(rmax_i-gmax)/total ----------
__global__ void k_gred(const float* __restrict__ rowmax, const float* __restrict__ rowsum,
                       float* __restrict__ rowscale) {
    int b = blockIdx.x, tid = threadIdx.x;   // 512
    __shared__ float mred[512], sred[512];
    float m = (tid < N_) ? rowmax[b * N_ + tid] : -1e30f;
    float s = (tid < N_) ? rowsum[b * N_ + tid] : 0.f;
    mred[tid] = m;
    __syncthreads();
    for (int st = 256; st > 0; st >>= 1) {
        if (tid < st) mred[tid] = fmaxf(mred[tid], mred[tid + st]);
        __syncthreads();
    }
    float gm = mred[0];
    sred[tid] = s * expf(m - gm);
    __syncthreads();
    for (int st = 256; st > 0; st >>= 1) {
        if (tid < st) sred[tid] += sred[tid + st];
        __syncthreads();
    }
    float inv = 1.f / sred[0];
    if (tid < N_) rowscale[b * N_ + tid] = expf(m - gm) * inv;
}

// -------------------- k_xlite: att normalize + accI + final combine --------------------
// x = 0.5*(xpart*rowscale + s*vb2) + 0.25*(s*in_i + att@inp), s = rowsum*rowscale
__global__ __launch_bounds__(256) void k_xlite(
    const float* __restrict__ inp, const float* __restrict__ vb2,
    float* __restrict__ scoresAtt, const float* __restrict__ rowmax,
    const float* __restrict__ rowsum, const float* __restrict__ rowscale,
    const float* __restrict__ xpart, float* __restrict__ xout) {
    int i = blockIdx.x, b = blockIdx.y;
    int tid = threadIdx.x;
    __shared__ float aLds[N_];
    __shared__ float accIp[256];

    const float rmaxI = rowmax[b * N_ + i];
    const float rscaleI = rowscale[b * N_ + i];
    float* scoreRow = scoresAtt + (size_t)(b * N_ + i) * N_;

    {
        float sc = scoreRow[tid];
        float a = expf(sc - rmaxI) * rscaleI;
        scoreRow[tid] = a; aLds[tid] = a;
        if (tid < N_ - 256) {
            float sc2 = scoreRow[tid + 256];
            float a2 = expf(sc2 - rmaxI) * rscaleI;
            scoreRow[tid + 256] = a2; aLds[tid + 256] = a2;
        }
    }
    __syncthreads();

    int f = tid & 63, q = tid >> 6;
    float aI = 0.f;
    const float* inB = inp + (size_t)b * N_ * F_;
    for (int j = q * 96; j < q * 96 + 96; ++j)
        aI = fmaf(aLds[j], inB[j * F_ + f], aI);
    accIp[tid] = aI;
    __syncthreads();

    if (tid < F_) {
        float accI = accIp[tid] + accIp[64 + tid] + accIp[128 + tid] + accIp[192 + tid];
        float s = rowsum[b * N_ + i] * rscaleI;
        float xp = xpart[(size_t)(b * N_ + i) * F_ + tid] * rscaleI;
        float r = 0.5f * (xp + s * vb2[tid]) +
                  0.25f * (s * inB[(size_t)i * F_ + tid] + accI);
        xout[(size_t)(b * N_ + i) * F_ + tid] = r;
    }
}

// -------------------- launch --------------------

extern "C" void kernel_launch(void* const* d_in, const int* in_sizes, int n_in,
                              void* d_out, int out_size, void* d_ws, size_t ws_size,
                              hipStream_t stream) {
    const float* inp   = (const float*)d_in[0];
    const float* pos   = (const float*)d_in[1];
    const float* vW1   = (const float*)d_in[2];
    const float* vb1   = (const float*)d_in[3];
    const float* vg    = (const float*)d_in[4];
    const float* vbeta = (const float*)d_in[5];
    const float* vW2   = (const float*)d_in[6];
    const float* vb2   = (const float*)d_in[7];
    const float* sW1   = (const float*)d_in[8];
    const float* sb1   = (const float*)d_in[9];
    const float* sW2   = (const float*)d_in[10];
    const float* sb2   = (const float*)d_in[11];

    float* xout   = (float*)d_out;                 // B*N*F
    float* attout = xout + B_ * N_ * F_;           // B*N*N (scores -> att in place)

    unsigned short* W2hT   = (unsigned short*)d_ws;                  // 32KB fp16
    unsigned int*   coeffP = (unsigned int*)((char*)d_ws + 32768);   // 1KB packed f16x2
    float*          scal   = (float*)((char*)d_ws + 33792);          // 6 scalars (pad)
    unsigned int*   sw16   = (unsigned int*)((char*)d_ws + 34048);   // 64 uints (256B)
    unsigned int*   t16    = (unsigned int*)((char*)d_ws + 34304);   // B*N*64 uints (768KB)
    float* rowmax   = (float*)((char*)d_ws + 34304 + B_ * N_ * 64 * 4);
    float* rowsum   = rowmax + B_ * N_;
    float* rowscale = rowsum + B_ * N_;
    float* xpart    = rowscale + B_ * N_;          // B*N*64 fp32 (768KB)

    k_prep<<<B_ * N_ + 128 + 1, 128, 0, stream>>>(
        inp, sW1, vb2, sb1, vW2, vW1, vb1, vg, vbeta, sW2,
        t16, W2hT, coeffP, scal, sw16);
    k_scores<<<dim3(96, B_), 256, 0, stream>>>(
        pos, coeffP, scal, W2hT, vW2, t16, sw16, sb2, attout, rowmax, rowsum, xpart);
    k_gred<<<B_, 512, 0, stream>>>(rowmax, rowsum, rowscale);
    k_xlite<<<dim3(N_, B_), 256, 0, stream>>>(inp, vb2, attout, rowmax, rowsum,
                                              rowscale, xpart, xout);
}

// Round 19
// 130.510 us; speedup vs baseline: 5.9629x; 1.1040x over previous
//
#include <hip/hip_runtime.h>
#include <hip/hip_bf16.h>
#include <math.h>

#define B_ 8
#define N_ 384
#define F_ 64
#define H_ 128
#define LN_EPS 1e-5f

typedef _Float16 f16;
typedef f16 f16x2 __attribute__((ext_vector_type(2)));
typedef f16 f16x4 __attribute__((ext_vector_type(4)));
typedef f16 f16x8 __attribute__((ext_vector_type(8)));
typedef float f32x4v __attribute__((ext_vector_type(4)));

static __device__ __forceinline__ f16x2 u2h(unsigned int u) {
    union { unsigned int u; f16x2 h; } c; c.u = u; return c.h;
}
static __device__ __forceinline__ unsigned int h2u(f16 a, f16 b) {
    union { f16x2 h; unsigned int u; } c; c.h = (f16x2){a, b}; return c.u;
}
static __device__ __forceinline__ unsigned int x2u(f16x2 h) {
    union { f16x2 h; unsigned int u; } c; c.h = h; return c.u;
}
// packed f32->f16x2 (round-toward-zero packer, single VALU op)
static __device__ __forceinline__ f16x2 pk2(float a, float b) {
    auto r = __builtin_amdgcn_cvt_pkrtz(a, b);
    union { decltype(r) r; f16x2 h; } c; c.r = r; return c.h;
}

// packed-permuted index helpers: uint slot u = h4*16 + mf*2 + p packs
// elements (n, n+1) with n = mf*16 + h4*4 + 2p  (matches MFMA C/D row layout)
static __device__ __forceinline__ void perm_idx(int m, int& u, int& n0) {
    int h4 = (m >> 1) & 3, mf = m >> 3, p = m & 1;
    u = h4 * 16 + mf * 2 + p;
    n0 = mf * 16 + h4 * 4 + 2 * p;
}

// -------------------- fused setup kernel --------------------
__global__ __launch_bounds__(128) void k_prep(
    const float* __restrict__ inp, const float* __restrict__ sW1,
    const float* __restrict__ vb2, const float* __restrict__ sb1,
    const float* __restrict__ vW2, const float* __restrict__ vW1,
    const float* __restrict__ vb1, const float* __restrict__ vg,
    const float* __restrict__ vbeta, const float* __restrict__ sW2,
    unsigned int* __restrict__ t16, unsigned short* __restrict__ W2hT,
    unsigned int* __restrict__ coeffP, float* __restrict__ scal,
    unsigned int* __restrict__ sw16) {
    __shared__ float red[128];
    __shared__ float caS[128], cbS[128], ccS[128];
    const int bx = blockIdx.x;
    const int tid = threadIdx.x;

    if (bx < B_ * N_) {
        // tt[n] = 0.25*(in[row]+vb2)@sW1[:,n] + 0.5*sb1[n] ; pack-permute to t16
        int row = bx, n = tid;
        float acc = 0.f;
#pragma unroll
        for (int f = 0; f < F_; ++f)
            acc = fmaf(0.25f * (inp[row * F_ + f] + vb2[f]), sW1[f * H_ + n], acc);
        red[n] = acc + 0.5f * sb1[n];
        __syncthreads();
        if (tid < 64) {
            int u, n0; perm_idx(tid, u, n0);
            t16[row * 64 + u] = h2u((f16)red[n0], (f16)red[n0 + 1]);
        }
        return;
    }
    if (bx < B_ * N_ + 128) {
        int idx = (bx - B_ * N_) * 128 + tid;
        int k = idx >> 7, n = idx & 127;
        float acc = 0.f;
#pragma unroll
        for (int f = 0; f < F_; ++f) acc = fmaf(vW2[k * F_ + f], sW1[f * H_ + n], acc);
        f16 hv = (f16)(0.5f * acc);
        W2hT[n * H_ + k] = *reinterpret_cast<unsigned short*>(&hv);
        return;
    }

    // ---- algebraic-LN coefficients + sw16 ----
    const int d = tid;   // 128
    float a = vW1[d], bb = vW1[H_ + d], c = vb1[d];
    float mA, mB, mC, Saa, Sbb, Scc, Sab, Sac, Sbc;
    float ca, cb, cc;
#define BMEAN(OUT, VAL)                                                  \
    red[d] = (VAL); __syncthreads();                                     \
    for (int st = 64; st > 0; st >>= 1) {                                \
        if (d < st) red[d] += red[d + st];                               \
        __syncthreads();                                                 \
    }                                                                    \
    OUT = red[0] * (1.f / 128.f); __syncthreads();

    BMEAN(mA, a); BMEAN(mB, bb); BMEAN(mC, c);
    ca = a - mA; cb = bb - mB; cc = c - mC;
    caS[d] = ca * vg[d]; cbS[d] = cb * vg[d]; ccS[d] = cc * vg[d];
    BMEAN(Saa, ca * ca); BMEAN(Sbb, cb * cb); BMEAN(Scc, cc * cc);
    BMEAN(Sab, ca * cb); BMEAN(Sac, ca * cc); BMEAN(Sbc, cb * cc);
#undef BMEAN
    __syncthreads();
    if (d < 64) {
        int d0 = 2 * d;
        coeffP[d]       = h2u((f16)caS[d0], (f16)caS[d0 + 1]);
        coeffP[64 + d]  = h2u((f16)cbS[d0], (f16)cbS[d0 + 1]);
        coeffP[128 + d] = h2u((f16)ccS[d0], (f16)ccS[d0 + 1]);
        coeffP[192 + d] = h2u((f16)vbeta[d0], (f16)vbeta[d0 + 1]);
        int u, n0; perm_idx(d, u, n0);
        sw16[u] = h2u((f16)sW2[n0], (f16)sW2[n0 + 1]);
    }
    if (d == 0) {
        scal[0] = Saa; scal[1] = Sbb; scal[2] = Scc;
        scal[3] = Sab; scal[4] = Sac; scal[5] = Sbc;
    }
}

// -------------------- phase 1: scores + flash accH (R18 base + packed-fp16 VALU diet) ----
// R18 config (bF software pipeline, coeff resident, vW2 fp32 LDS, no launch-bound cap).
// NEW (VALU cut, counters said VALU=52.8% dominant): phaseC fully packed fp16
// (cvt_pkrtz + pk ops), flash accH packed fp16 (16 pk_fma/tile), fp32 acc-init resident.
// Precision budget: x scale 6.5e-3 vs 1.3e-4 threshold — fp16 noise ~1e-5 on x.
#define VW2_OFF 32768
__global__ __launch_bounds__(256) void k_scores(
    const float* __restrict__ pos, const unsigned int* __restrict__ coeffP,
    const float* __restrict__ scal, const unsigned short* __restrict__ W2hT,
    const float* __restrict__ vW2, const unsigned int* __restrict__ t16,
    const unsigned int* __restrict__ sw16, const float* __restrict__ sb2,
    float* __restrict__ scores, float* __restrict__ rowmax,
    float* __restrict__ rowsum, float* __restrict__ xpart) {
    __shared__ __align__(16) char smem[65536];   // 32KB W' (swizzled) + 32KB vW2 fp32

    const int tid = threadIdx.x;
    const int b = blockIdx.y;
    const int w = tid >> 6, lane = tid & 63;
    const int i = blockIdx.x * 4 + w;
    const int ln = lane & 15, h4 = lane >> 4;

    // ---- one-time stage: W' swizzled + vW2 fp32 ----
#pragma unroll
    for (int s = 0; s < 8; ++s) {
        int idx = tid + s * 256;
        int n = idx >> 4, c = idx & 15;
        uint4 v = *(const uint4*)(W2hT + n * H_ + c * 8);
        *(uint4*)(smem + ((n * 256 + c * 16) ^ ((n & 7) << 4))) = v;
    }
#pragma unroll
    for (int s = 0; s < 8; ++s) {
        int idx = tid + s * 256;            // 0..2047 float4 chunks of vW2 (128x64)
        uint4 v = *(const uint4*)((const float*)vW2 + idx * 4);
        *(uint4*)(smem + VW2_OFF + idx * 16) = v;
    }
    __syncthreads();

    // ---- resident state ----
    uint4 cagR[4], cbgR[4], ccgR[4], vbR[4];
#pragma unroll
    for (int kc = 0; kc < 4; ++kc) {
        cagR[kc] = *(const uint4*)(coeffP + kc * 16 + h4 * 4);
        cbgR[kc] = *(const uint4*)(coeffP + 64 + kc * 16 + h4 * 4);
        ccgR[kc] = *(const uint4*)(coeffP + 128 + kc * 16 + h4 * 4);
        vbR[kc]  = *(const uint4*)(coeffP + 192 + kc * 16 + h4 * 4);
    }
    // acc-init (= ti) resident in fp32 — no per-tile unpack
    f32x4v acc0[8];
    {
        const unsigned int* tiP = t16 + (size_t)(b * N_ + i) * 64 + h4 * 16;
#pragma unroll
        for (int s = 0; s < 4; ++s) {
            uint4 v = *(const uint4*)(tiP + s * 4);
            f16x2 a0 = u2h(v.x), a1 = u2h(v.y), a2 = u2h(v.z), a3 = u2h(v.w);
            acc0[s * 2][0] = (float)a0[0]; acc0[s * 2][1] = (float)a0[1];
            acc0[s * 2][2] = (float)a1[0]; acc0[s * 2][3] = (float)a1[1];
            acc0[s * 2 + 1][0] = (float)a2[0]; acc0[s * 2 + 1][1] = (float)a2[1];
            acc0[s * 2 + 1][2] = (float)a3[0]; acc0[s * 2 + 1][3] = (float)a3[1];
        }
    }
    uint2 swR[8];
#pragma unroll
    for (int mf = 0; mf < 8; ++mf)
        swR[mf] = *(const uint2*)(sw16 + h4 * 16 + mf * 2);

    const float Saa = scal[0], Sbb = scal[1], Scc = scal[2];
    const float Sab = scal[3], Sac = scal[4], Sbc = scal[5];
    const float sb2v = sb2[0];

    const float* pi = pos + (size_t)(b * N_ + i) * 3;
    const float ax = pi[0], ay = pi[1], az = pi[2];
    float* scoreRow = scores + (size_t)(b * N_ + i) * N_;

    float m_run = -1e30f, s_run = 0.f;
    unsigned int accPh[16];                    // packed f16x2 accH (kc*4 + e/2)
#pragma unroll
    for (int k = 0; k < 16; ++k) accPh[k] = 0u;

    // bF construction from a given j-pos (uses resident coeffs)
    auto makeBF = [&](float bx, float by, float bz, f16x8 (&bF)[4]) {
        float dotv = ax * bx + ay * by + az * bz;
        float cx = ay * bz - az * by;
        float cy = az * bx - ax * bz;
        float cz = ax * by - ay * bx;
        float cns = cx * cx + cy * cy + cz * cz;
        float cn = sqrtf(cns);
        float var = Saa * dotv * dotv + Sbb * cns + Scc +
                    2.f * (Sab * dotv * cn + Sac * dotv + Sbc * cn);
        float rstd = rsqrtf(var + LN_EPS);
        f16 d2 = (f16)(dotv * rstd), c2 = (f16)(cn * rstd), r2 = (f16)rstd;
        f16x2 D2 = {d2, d2}, C2 = {c2, c2}, R2 = {r2, r2};
        const f16x2 Z = {(f16)0.f, (f16)0.f};
#pragma unroll
        for (int kc = 0; kc < 4; ++kc) {
            f16x2 vp0 = __builtin_elementwise_max(D2 * u2h(cagR[kc].x) + (C2 * u2h(cbgR[kc].x) + (R2 * u2h(ccgR[kc].x) + u2h(vbR[kc].x))), Z);
            f16x2 vp1 = __builtin_elementwise_max(D2 * u2h(cagR[kc].y) + (C2 * u2h(cbgR[kc].y) + (R2 * u2h(ccgR[kc].y) + u2h(vbR[kc].y))), Z);
            f16x2 vp2 = __builtin_elementwise_max(D2 * u2h(cagR[kc].z) + (C2 * u2h(cbgR[kc].z) + (R2 * u2h(ccgR[kc].z) + u2h(vbR[kc].z))), Z);
            f16x2 vp3 = __builtin_elementwise_max(D2 * u2h(cagR[kc].w) + (C2 * u2h(cbgR[kc].w) + (R2 * u2h(ccgR[kc].w) + u2h(vbR[kc].w))), Z);
            f16x4 q01 = __builtin_shufflevector(vp0, vp1, 0, 1, 2, 3);
            f16x4 q23 = __builtin_shufflevector(vp2, vp3, 0, 1, 2, 3);
            bF[kc] = __builtin_shufflevector(q01, q23, 0, 1, 2, 3, 4, 5, 6, 7);
        }
    };

    // ---- prologue: bF for tile 0; pos prefetch for tile 1 ----
    f16x8 bF_cur[4], bF_nxt[4];
    float bx, by, bz;
    {
        const float* p0 = pos + (size_t)(b * N_ + ln) * 3;
        bx = p0[0]; by = p0[1]; bz = p0[2];
    }
    makeBF(bx, by, bz, bF_cur);
    {
        const float* p1 = pos + (size_t)(b * N_ + 16 + ln) * 3;
        bx = p1[0]; by = p1[1]; bz = p1[2];
    }

#pragma unroll 1
    for (int jt = 0; jt < 24; ++jt) {
        const int j0 = jt * 16;

        // ---- tj prefetch (packed), consumed at phaseC ----
        const unsigned int* tjP = t16 + (size_t)(b * N_ + j0 + ln) * 64 + h4 * 16;
        uint4 tj0 = *(const uint4*)(tjP);
        uint4 tj1 = *(const uint4*)(tjP + 4);
        uint4 tj2 = *(const uint4*)(tjP + 8);
        uint4 tj3 = *(const uint4*)(tjP + 12);

        // ---- acc init = resident fp32 ti ----
        f32x4v acc[8];
#pragma unroll
        for (int mf = 0; mf < 8; ++mf) acc[mf] = acc0[mf];

        // ---- GEMM: A from LDS, B = bF_cur ----
#pragma unroll
        for (int kc = 0; kc < 4; ++kc) {
            const int kb = (kc * 64 + h4 * 16) ^ ((ln & 7) << 4);
#pragma unroll
            for (int mf = 0; mf < 8; ++mf) {
                f16x8 aFr = *(const f16x8*)(smem + (mf * 16 + ln) * 256 + kb);
                acc[mf] = __builtin_amdgcn_mfma_f32_16x16x32_f16(aFr, bF_cur[kc], acc[mf], 0, 0, 0);
            }
        }

        // ---- construct NEXT tile's bF while MFMAs drain (independent VALU) ----
        f16x8 bF_hold[4];
#pragma unroll
        for (int kc = 0; kc < 4; ++kc) bF_hold[kc] = bF_cur[kc];
        {
            float gx = bx, gy = by, gz = bz;
            int jn2 = (jt + 2 < 24) ? (jt + 2) : 23;
            const float* pn = pos + (size_t)(b * N_ + jn2 * 16 + ln) * 3;
            bx = pn[0]; by = pn[1]; bz = pn[2];
            makeBF(gx, gy, gz, bF_nxt);
        }
#pragma unroll
        for (int kc = 0; kc < 4; ++kc) bF_cur[kc] = bF_nxt[kc];

        // ---- phaseC (packed fp16): relu(acc+tj) dot sw; reduce over h4 ----
        unsigned int tju[16] = {tj0.x, tj0.y, tj0.z, tj0.w, tj1.x, tj1.y, tj1.z, tj1.w,
                                tj2.x, tj2.y, tj2.z, tj2.w, tj3.x, tj3.y, tj3.z, tj3.w};
        const f16x2 Z = {(f16)0.f, (f16)0.f};
        f16x2 psA = Z, psB = Z;
#pragma unroll
        for (int mf = 0; mf < 8; ++mf) {
            f16x2 p01 = pk2(acc[mf][0], acc[mf][1]);
            f16x2 p23 = pk2(acc[mf][2], acc[mf][3]);
            f16x2 r01 = __builtin_elementwise_max(p01 + u2h(tju[mf * 2]), Z);
            f16x2 r23 = __builtin_elementwise_max(p23 + u2h(tju[mf * 2 + 1]), Z);
            if (mf < 4) {
                psA = r01 * u2h(swR[mf].x) + (r23 * u2h(swR[mf].y) + psA);
            } else {
                psB = r01 * u2h(swR[mf].x) + (r23 * u2h(swR[mf].y) + psB);
            }
        }
        float part = (float)psA[0] + (float)psA[1] + (float)psB[0] + (float)psB[1];
        part += __shfl_xor(part, 16);
        part += __shfl_xor(part, 32);
        float sc = part + sb2v;
        if (h4 == 0) scoreRow[j0 + ln] = sc;

        // ---- online stats + flash accH accumulate (packed fp16, of relu_h = bF_hold) ----
        float mn = fmaxf(m_run, sc);
        float a = expf(sc - mn);
        if (mn > m_run) {
            float sca = expf(m_run - mn);
            f16 sh = (f16)sca;
            f16x2 S2 = {sh, sh};
#pragma unroll
            for (int k = 0; k < 16; ++k) accPh[k] = x2u(u2h(accPh[k]) * S2);
            s_run *= sca;
        }
        s_run += a;
        m_run = mn;
        {
            f16 ah = (f16)a;
            f16x2 A2 = {ah, ah};
#pragma unroll
            for (int kc = 0; kc < 4; ++kc) {
                union { f16x8 v; uint4 u; } bc; bc.v = bF_hold[kc];
                accPh[kc * 4 + 0] = x2u(u2h(bc.u.x) * A2 + u2h(accPh[kc * 4 + 0]));
                accPh[kc * 4 + 1] = x2u(u2h(bc.u.y) * A2 + u2h(accPh[kc * 4 + 1]));
                accPh[kc * 4 + 2] = x2u(u2h(bc.u.z) * A2 + u2h(accPh[kc * 4 + 2]));
                accPh[kc * 4 + 3] = x2u(u2h(bc.u.w) * A2 + u2h(accPh[kc * 4 + 3]));
            }
        }
    }

    // ---- unpack accH to fp32 ----
    float accH[4][8];
#pragma unroll
    for (int kc = 0; kc < 4; ++kc)
#pragma unroll
        for (int p = 0; p < 4; ++p) {
            f16x2 v = u2h(accPh[kc * 4 + p]);
            accH[kc][2 * p] = (float)v[0];
            accH[kc][2 * p + 1] = (float)v[1];
        }

    // ---- epilogue: merge over ln bits — max first, single rescale, tree sums ----
    float m_tot = m_run;
#pragma unroll
    for (int d = 1; d < 16; d <<= 1) m_tot = fmaxf(m_tot, __shfl_xor(m_tot, d));
    float fsc = expf(m_run - m_tot);
    s_run *= fsc;
#pragma unroll
    for (int kc = 0; kc < 4; ++kc)
#pragma unroll
        for (int e = 0; e < 8; ++e) accH[kc][e] *= fsc;
#pragma unroll
    for (int d = 1; d < 16; d <<= 1) {
        s_run += __shfl_xor(s_run, d);
#pragma unroll
        for (int kc = 0; kc < 4; ++kc)
#pragma unroll
            for (int e = 0; e < 8; ++e) accH[kc][e] += __shfl_xor(accH[kc][e], d);
    }
    if (lane == 0) {
        rowmax[b * N_ + i] = m_tot;
        rowsum[b * N_ + i] = s_run;
    }

    // ---- accH @ vW2 (fp32, LDS): lane (ln,h4) dims d=kc*32+h4*8+e -> f=ln*4..+3 ----
    float xp0 = 0.f, xp1 = 0.f, xp2 = 0.f, xp3 = 0.f;
#pragma unroll
    for (int kc = 0; kc < 4; ++kc) {
#pragma unroll
        for (int e = 0; e < 8; ++e) {
            int dIdx = kc * 32 + h4 * 8 + e;
            float av = accH[kc][e];
            float4 wv = *(const float4*)(smem + VW2_OFF + dIdx * 256 + ln * 16);
            xp0 = fmaf(av, wv.x, xp0); xp1 = fmaf(av, wv.y, xp1);
            xp2 = fmaf(av, wv.z, xp2); xp3 = fmaf(av, wv.w, xp3);
        }
    }
    xp0 += __shfl_xor(xp0, 16); xp0 += __shfl_xor(xp0, 32);
    xp1 += __shfl_xor(xp1, 16); xp1 += __shfl_xor(xp1, 32);
    xp2 += __shfl_xor(xp2, 16); xp2 += __shfl_xor(xp2, 32);
    xp3 += __shfl_xor(xp3, 16); xp3 += __shfl_xor(xp3, 32);
    if (h4 == 0) {
        float4 o = {xp0, xp1, xp2, xp3};
        *(float4*)(xpart + (size_t)(b * N_ + i) * F_ + ln * 4) = o;
    }
}

// -------------------- per-batch softmax reduce: rowscale_i = exp(rmax_i-gmax)/total ----------
__global__ void k_gred(const float* __restrict__ rowmax, const float* __restrict__ rowsum,
                       float* __restrict__ rowscale) {
    int b = blockIdx.x, tid = threadIdx.x;   // 512
    __shared__ float mred[512], sred[512];
    float m = (tid < N_) ? rowmax[b * N_ + tid] : -1e30f;
    float s = (tid < N_) ? rowsum[b * N_ + tid] : 0.f;
    mred[tid] = m;
    __syncthreads();
    for (int st = 256; st > 0; st >>= 1) {
        if (tid < st) mred[tid] = fmaxf(mred[tid], mred[tid + st]);
        __syncthreads();
    }
    float gm = mred[0];
    sred[tid] = s * expf(m - gm);
    __syncthreads();
    for (int st = 256; st > 0; st >>= 1) {
        if (tid < st) sred[tid] += sred[tid + st];
        __syncthreads();
    }
    float inv = 1.f / sred[0];
    if (tid < N_) rowscale[b * N_ + tid] = expf(m - gm) * inv;
}

// -------------------- k_xlite: att normalize + accI + final combine --------------------
// x = 0.5*(xpart*rowscale + s*vb2) + 0.25*(s*in_i + att@inp), s = rowsum*rowscale
__global__ __launch_bounds__(256) void k_xlite(
    const float* __restrict__ inp, const float* __restrict__ vb2,
    float* __restrict__ scoresAtt, const float* __restrict__ rowmax,
    const float* __restrict__ rowsum, const float* __restrict__ rowscale,
    const float* __restrict__ xpart, float* __restrict__ xout) {
    int i = blockIdx.x, b = blockIdx.y;
    int tid = threadIdx.x;
    __shared__ float aLds[N_];
    __shared__ float accIp[256];

    const float rmaxI = rowmax[b * N_ + i];
    const float rscaleI = rowscale[b * N_ + i];
    float* scoreRow = scoresAtt + (size_t)(b * N_ + i) * N_;

    {
        float sc = scoreRow[tid];
        float a = expf(sc - rmaxI) * rscaleI;
        scoreRow[tid] = a; aLds[tid] = a;
        if (tid < N_ - 256) {
            float sc2 = scoreRow[tid + 256];
            float a2 = expf(sc2 - rmaxI) * rscaleI;
            scoreRow[tid + 256] = a2; aLds[tid + 256] = a2;
        }
    }
    __syncthreads();

    int f = tid & 63, q = tid >> 6;
    float aI = 0.f;
    const float* inB = inp + (size_t)b * N_ * F_;
    for (int j = q * 96; j < q * 96 + 96; ++j)
        aI = fmaf(aLds[j], inB[j * F_ + f], aI);
    accIp[tid] = aI;
    __syncthreads();

    if (tid < F_) {
        float accI = accIp[tid] + accIp[64 + tid] + accIp[128 + tid] + accIp[192 + tid];
        float s = rowsum[b * N_ + i] * rscaleI;
        float xp = xpart[(size_t)(b * N_ + i) * F_ + tid] * rscaleI;
        float r = 0.5f * (xp + s * vb2[tid]) +
                  0.25f * (s * inB[(size_t)i * F_ + tid] + accI);
        xout[(size_t)(b * N_ + i) * F_ + tid] = r;
    }
}

// -------------------- launch --------------------

extern "C" void kernel_launch(void* const* d_in, const int* in_sizes, int n_in,
                              void* d_out, int out_size, void* d_ws, size_t ws_size,
                              hipStream_t stream) {
    const float* inp   = (const float*)d_in[0];
    const float* pos   = (const float*)d_in[1];
    const float* vW1   = (const float*)d_in[2];
    const float* vb1   = (const float*)d_in[3];
    const float* vg    = (const float*)d_in[4];
    const float* vbeta = (const float*)d_in[5];
    const float* vW2   = (const float*)d_in[6];
    const float* vb2   = (const float*)d_in[7];
    const float* sW1   = (const float*)d_in[8];
    const float* sb1   = (const float*)d_in[9];
    const float* sW2   = (const float*)d_in[10];
    const float* sb2   = (const float*)d_in[11];

    float* xout   = (float*)d_out;                 // B*N*F
    float* attout = xout + B_ * N_ * F_;           // B*N*N (scores -> att in place)

    unsigned short* W2hT   = (unsigned short*)d_ws;                  // 32KB fp16
    unsigned int*   coeffP = (unsigned int*)((char*)d_ws + 32768);   // 1KB packed f16x2
    float*          scal   = (float*)((char*)d_ws + 33792);          // 6 scalars (pad)
    unsigned int*   sw16   = (unsigned int*)((char*)d_ws + 34048);   // 64 uints (256B)
    unsigned int*   t16    = (unsigned int*)((char*)d_ws + 34304);   // B*N*64 uints (768KB)
    float* rowmax   = (float*)((char*)d_ws + 34304 + B_ * N_ * 64 * 4);
    float* rowsum   = rowmax + B_ * N_;
    float* rowscale = rowsum + B_ * N_;
    float* xpart    = rowscale + B_ * N_;          // B*N*64 fp32 (768KB)

    k_prep<<<B_ * N_ + 128 + 1, 128, 0, stream>>>(
        inp, sW1, vb2, sb1, vW2, vW1, vb1, vg, vbeta, sW2,
        t16, W2hT, coeffP, scal, sw16);
    k_scores<<<dim3(96, B_), 256, 0, stream>>>(
        pos, coeffP, scal, W2hT, vW2, t16, sw16, sb2, attout, rowmax, rowsum, xpart);
    k_gred<<<B_, 512, 0, stream>>>(rowmax, rowsum, rowscale);
    k_xlite<<<dim3(N_, B_), 256, 0, stream>>>(inp, vb2, attout, rowmax, rowsum,
                                              rowscale, xpart, xout);
}

// Round 20
// 124.107 us; speedup vs baseline: 6.2705x; 1.0516x over previous
//
#include <hip/hip_runtime.h>
#include <hip/hip_bf16.h>
#include <math.h>

#define B_ 8
#define N_ 384
#define F_ 64
#define H_ 128
#define LN_EPS 1e-5f

typedef _Float16 f16;
typedef f16 f16x2 __attribute__((ext_vector_type(2)));
typedef f16 f16x4 __attribute__((ext_vector_type(4)));
typedef f16 f16x8 __attribute__((ext_vector_type(8)));
typedef float f32x4v __attribute__((ext_vector_type(4)));

static __device__ __forceinline__ f16x2 u2h(unsigned int u) {
    union { unsigned int u; f16x2 h; } c; c.u = u; return c.h;
}
static __device__ __forceinline__ unsigned int h2u(f16 a, f16 b) {
    union { f16x2 h; unsigned int u; } c; c.h = (f16x2){a, b}; return c.u;
}
static __device__ __forceinline__ unsigned int x2u(f16x2 h) {
    union { f16x2 h; unsigned int u; } c; c.h = h; return c.u;
}
// packed f32->f16x2 (round-toward-zero packer, single VALU op)
static __device__ __forceinline__ f16x2 pk2(float a, float b) {
    auto r = __builtin_amdgcn_cvt_pkrtz(a, b);
    union { decltype(r) r; f16x2 h; } c; c.r = r; return c.h;
}

// packed-permuted index helpers: uint slot u = h4*16 + mf*2 + p packs
// elements (n, n+1) with n = mf*16 + h4*4 + 2p  (matches MFMA C/D row layout)
static __device__ __forceinline__ void perm_idx(int m, int& u, int& n0) {
    int h4 = (m >> 1) & 3, mf = m >> 3, p = m & 1;
    u = h4 * 16 + mf * 2 + p;
    n0 = mf * 16 + h4 * 4 + 2 * p;
}

// -------------------- fused setup kernel --------------------
__global__ __launch_bounds__(128) void k_prep(
    const float* __restrict__ inp, const float* __restrict__ sW1,
    const float* __restrict__ vb2, const float* __restrict__ sb1,
    const float* __restrict__ vW2, const float* __restrict__ vW1,
    const float* __restrict__ vb1, const float* __restrict__ vg,
    const float* __restrict__ vbeta, const float* __restrict__ sW2,
    unsigned int* __restrict__ t16, unsigned short* __restrict__ W2hT,
    unsigned int* __restrict__ coeffP, float* __restrict__ scal,
    unsigned int* __restrict__ sw16) {
    __shared__ float red[128];
    __shared__ float caS[128], cbS[128], ccS[128];
    const int bx = blockIdx.x;
    const int tid = threadIdx.x;

    if (bx < B_ * N_) {
        // tt[n] = 0.25*(in[row]+vb2)@sW1[:,n] + 0.5*sb1[n] ; pack-permute to t16
        int row = bx, n = tid;
        float acc = 0.f;
#pragma unroll
        for (int f = 0; f < F_; ++f)
            acc = fmaf(0.25f * (inp[row * F_ + f] + vb2[f]), sW1[f * H_ + n], acc);
        red[n] = acc + 0.5f * sb1[n];
        __syncthreads();
        if (tid < 64) {
            int u, n0; perm_idx(tid, u, n0);
            t16[row * 64 + u] = h2u((f16)red[n0], (f16)red[n0 + 1]);
        }
        return;
    }
    if (bx < B_ * N_ + 128) {
        int idx = (bx - B_ * N_) * 128 + tid;
        int k = idx >> 7, n = idx & 127;
        float acc = 0.f;
#pragma unroll
        for (int f = 0; f < F_; ++f) acc = fmaf(vW2[k * F_ + f], sW1[f * H_ + n], acc);
        f16 hv = (f16)(0.5f * acc);
        W2hT[n * H_ + k] = *reinterpret_cast<unsigned short*>(&hv);
        return;
    }

    // ---- algebraic-LN coefficients + sw16 ----
    const int d = tid;   // 128
    float a = vW1[d], bb = vW1[H_ + d], c = vb1[d];
    float mA, mB, mC, Saa, Sbb, Scc, Sab, Sac, Sbc;
    float ca, cb, cc;
#define BMEAN(OUT, VAL)                                                  \
    red[d] = (VAL); __syncthreads();                                     \
    for (int st = 64; st > 0; st >>= 1) {                                \
        if (d < st) red[d] += red[d + st];                               \
        __syncthreads();                                                 \
    }                                                                    \
    OUT = red[0] * (1.f / 128.f); __syncthreads();

    BMEAN(mA, a); BMEAN(mB, bb); BMEAN(mC, c);
    ca = a - mA; cb = bb - mB; cc = c - mC;
    caS[d] = ca * vg[d]; cbS[d] = cb * vg[d]; ccS[d] = cc * vg[d];
    BMEAN(Saa, ca * ca); BMEAN(Sbb, cb * cb); BMEAN(Scc, cc * cc);
    BMEAN(Sab, ca * cb); BMEAN(Sac, ca * cc); BMEAN(Sbc, cb * cc);
#undef BMEAN
    __syncthreads();
    if (d < 64) {
        int d0 = 2 * d;
        coeffP[d]       = h2u((f16)caS[d0], (f16)caS[d0 + 1]);
        coeffP[64 + d]  = h2u((f16)cbS[d0], (f16)cbS[d0 + 1]);
        coeffP[128 + d] = h2u((f16)ccS[d0], (f16)ccS[d0 + 1]);
        coeffP[192 + d] = h2u((f16)vbeta[d0], (f16)vbeta[d0 + 1]);
        int u, n0; perm_idx(d, u, n0);
        sw16[u] = h2u((f16)sW2[n0], (f16)sW2[n0 + 1]);
    }
    if (d == 0) {
        scal[0] = Saa; scal[1] = Sbb; scal[2] = Scc;
        scal[3] = Sab; scal[4] = Sac; scal[5] = Sbc;
    }
}

// -------------------- phase 1: scores + unshifted-exp accH --------------------
// R19 base (bF pipeline, packed-fp16 phaseC/accH, coeff resident, vW2 fp32 LDS, no
// launch-bound cap). NEW: flash max-tracking REMOVED — scores are O(1) for this
// problem, so a = exp(sc) unshifted is fp32-safe; softmax normalization deferred to
// a single per-batch total T_b (k_gred). Deletes per-tile fmax/rescale-branch and
// the max-merge epilogue; rowmax buffer gone.
#define VW2_OFF 32768
__global__ __launch_bounds__(256) void k_scores(
    const float* __restrict__ pos, const unsigned int* __restrict__ coeffP,
    const float* __restrict__ scal, const unsigned short* __restrict__ W2hT,
    const float* __restrict__ vW2, const unsigned int* __restrict__ t16,
    const unsigned int* __restrict__ sw16, const float* __restrict__ sb2,
    float* __restrict__ scores, float* __restrict__ rowsum,
    float* __restrict__ xpart) {
    __shared__ __align__(16) char smem[65536];   // 32KB W' (swizzled) + 32KB vW2 fp32

    const int tid = threadIdx.x;
    const int b = blockIdx.y;
    const int w = tid >> 6, lane = tid & 63;
    const int i = blockIdx.x * 4 + w;
    const int ln = lane & 15, h4 = lane >> 4;

    // ---- one-time stage: W' swizzled + vW2 fp32 ----
#pragma unroll
    for (int s = 0; s < 8; ++s) {
        int idx = tid + s * 256;
        int n = idx >> 4, c = idx & 15;
        uint4 v = *(const uint4*)(W2hT + n * H_ + c * 8);
        *(uint4*)(smem + ((n * 256 + c * 16) ^ ((n & 7) << 4))) = v;
    }
#pragma unroll
    for (int s = 0; s < 8; ++s) {
        int idx = tid + s * 256;            // 0..2047 float4 chunks of vW2 (128x64)
        uint4 v = *(const uint4*)((const float*)vW2 + idx * 4);
        *(uint4*)(smem + VW2_OFF + idx * 16) = v;
    }
    __syncthreads();

    // ---- resident state ----
    uint4 cagR[4], cbgR[4], ccgR[4], vbR[4];
#pragma unroll
    for (int kc = 0; kc < 4; ++kc) {
        cagR[kc] = *(const uint4*)(coeffP + kc * 16 + h4 * 4);
        cbgR[kc] = *(const uint4*)(coeffP + 64 + kc * 16 + h4 * 4);
        ccgR[kc] = *(const uint4*)(coeffP + 128 + kc * 16 + h4 * 4);
        vbR[kc]  = *(const uint4*)(coeffP + 192 + kc * 16 + h4 * 4);
    }
    // acc-init (= ti) resident in fp32 — no per-tile unpack
    f32x4v acc0[8];
    {
        const unsigned int* tiP = t16 + (size_t)(b * N_ + i) * 64 + h4 * 16;
#pragma unroll
        for (int s = 0; s < 4; ++s) {
            uint4 v = *(const uint4*)(tiP + s * 4);
            f16x2 a0 = u2h(v.x), a1 = u2h(v.y), a2 = u2h(v.z), a3 = u2h(v.w);
            acc0[s * 2][0] = (float)a0[0]; acc0[s * 2][1] = (float)a0[1];
            acc0[s * 2][2] = (float)a1[0]; acc0[s * 2][3] = (float)a1[1];
            acc0[s * 2 + 1][0] = (float)a2[0]; acc0[s * 2 + 1][1] = (float)a2[1];
            acc0[s * 2 + 1][2] = (float)a3[0]; acc0[s * 2 + 1][3] = (float)a3[1];
        }
    }
    uint2 swR[8];
#pragma unroll
    for (int mf = 0; mf < 8; ++mf)
        swR[mf] = *(const uint2*)(sw16 + h4 * 16 + mf * 2);

    const float Saa = scal[0], Sbb = scal[1], Scc = scal[2];
    const float Sab = scal[3], Sac = scal[4], Sbc = scal[5];
    const float sb2v = sb2[0];

    const float* pi = pos + (size_t)(b * N_ + i) * 3;
    const float ax = pi[0], ay = pi[1], az = pi[2];
    float* scoreRow = scores + (size_t)(b * N_ + i) * N_;

    float s_run = 0.f;
    unsigned int accPh[16];                    // packed f16x2 accH (kc*4 + e/2)
#pragma unroll
    for (int k = 0; k < 16; ++k) accPh[k] = 0u;

    // bF construction from a given j-pos (uses resident coeffs)
    auto makeBF = [&](float bx, float by, float bz, f16x8 (&bF)[4]) {
        float dotv = ax * bx + ay * by + az * bz;
        float cx = ay * bz - az * by;
        float cy = az * bx - ax * bz;
        float cz = ax * by - ay * bx;
        float cns = cx * cx + cy * cy + cz * cz;
        float cn = sqrtf(cns);
        float var = Saa * dotv * dotv + Sbb * cns + Scc +
                    2.f * (Sab * dotv * cn + Sac * dotv + Sbc * cn);
        float rstd = rsqrtf(var + LN_EPS);
        f16 d2 = (f16)(dotv * rstd), c2 = (f16)(cn * rstd), r2 = (f16)rstd;
        f16x2 D2 = {d2, d2}, C2 = {c2, c2}, R2 = {r2, r2};
        const f16x2 Z = {(f16)0.f, (f16)0.f};
#pragma unroll
        for (int kc = 0; kc < 4; ++kc) {
            f16x2 vp0 = __builtin_elementwise_max(D2 * u2h(cagR[kc].x) + (C2 * u2h(cbgR[kc].x) + (R2 * u2h(ccgR[kc].x) + u2h(vbR[kc].x))), Z);
            f16x2 vp1 = __builtin_elementwise_max(D2 * u2h(cagR[kc].y) + (C2 * u2h(cbgR[kc].y) + (R2 * u2h(ccgR[kc].y) + u2h(vbR[kc].y))), Z);
            f16x2 vp2 = __builtin_elementwise_max(D2 * u2h(cagR[kc].z) + (C2 * u2h(cbgR[kc].z) + (R2 * u2h(ccgR[kc].z) + u2h(vbR[kc].z))), Z);
            f16x2 vp3 = __builtin_elementwise_max(D2 * u2h(cagR[kc].w) + (C2 * u2h(cbgR[kc].w) + (R2 * u2h(ccgR[kc].w) + u2h(vbR[kc].w))), Z);
            f16x4 q01 = __builtin_shufflevector(vp0, vp1, 0, 1, 2, 3);
            f16x4 q23 = __builtin_shufflevector(vp2, vp3, 0, 1, 2, 3);
            bF[kc] = __builtin_shufflevector(q01, q23, 0, 1, 2, 3, 4, 5, 6, 7);
        }
    };

    // ---- prologue: bF for tile 0; pos prefetch for tile 1 ----
    f16x8 bF_cur[4], bF_nxt[4];
    float bx, by, bz;
    {
        const float* p0 = pos + (size_t)(b * N_ + ln) * 3;
        bx = p0[0]; by = p0[1]; bz = p0[2];
    }
    makeBF(bx, by, bz, bF_cur);
    {
        const float* p1 = pos + (size_t)(b * N_ + 16 + ln) * 3;
        bx = p1[0]; by = p1[1]; bz = p1[2];
    }

#pragma unroll 1
    for (int jt = 0; jt < 24; ++jt) {
        const int j0 = jt * 16;

        // ---- tj prefetch (packed), consumed at phaseC ----
        const unsigned int* tjP = t16 + (size_t)(b * N_ + j0 + ln) * 64 + h4 * 16;
        uint4 tj0 = *(const uint4*)(tjP);
        uint4 tj1 = *(const uint4*)(tjP + 4);
        uint4 tj2 = *(const uint4*)(tjP + 8);
        uint4 tj3 = *(const uint4*)(tjP + 12);

        // ---- acc init = resident fp32 ti ----
        f32x4v acc[8];
#pragma unroll
        for (int mf = 0; mf < 8; ++mf) acc[mf] = acc0[mf];

        // ---- GEMM: A from LDS, B = bF_cur ----
#pragma unroll
        for (int kc = 0; kc < 4; ++kc) {
            const int kb = (kc * 64 + h4 * 16) ^ ((ln & 7) << 4);
#pragma unroll
            for (int mf = 0; mf < 8; ++mf) {
                f16x8 aFr = *(const f16x8*)(smem + (mf * 16 + ln) * 256 + kb);
                acc[mf] = __builtin_amdgcn_mfma_f32_16x16x32_f16(aFr, bF_cur[kc], acc[mf], 0, 0, 0);
            }
        }

        // ---- construct NEXT tile's bF while MFMAs drain (independent VALU) ----
        f16x8 bF_hold[4];
#pragma unroll
        for (int kc = 0; kc < 4; ++kc) bF_hold[kc] = bF_cur[kc];
        {
            float gx = bx, gy = by, gz = bz;
            int jn2 = (jt + 2 < 24) ? (jt + 2) : 23;
            const float* pn = pos + (size_t)(b * N_ + jn2 * 16 + ln) * 3;
            bx = pn[0]; by = pn[1]; bz = pn[2];
            makeBF(gx, gy, gz, bF_nxt);
        }
#pragma unroll
        for (int kc = 0; kc < 4; ++kc) bF_cur[kc] = bF_nxt[kc];

        // ---- phaseC (packed fp16): relu(acc+tj) dot sw; reduce over h4 ----
        unsigned int tju[16] = {tj0.x, tj0.y, tj0.z, tj0.w, tj1.x, tj1.y, tj1.z, tj1.w,
                                tj2.x, tj2.y, tj2.z, tj2.w, tj3.x, tj3.y, tj3.z, tj3.w};
        const f16x2 Z = {(f16)0.f, (f16)0.f};
        f16x2 psA = Z, psB = Z;
#pragma unroll
        for (int mf = 0; mf < 8; ++mf) {
            f16x2 p01 = pk2(acc[mf][0], acc[mf][1]);
            f16x2 p23 = pk2(acc[mf][2], acc[mf][3]);
            f16x2 r01 = __builtin_elementwise_max(p01 + u2h(tju[mf * 2]), Z);
            f16x2 r23 = __builtin_elementwise_max(p23 + u2h(tju[mf * 2 + 1]), Z);
            if (mf < 4) {
                psA = r01 * u2h(swR[mf].x) + (r23 * u2h(swR[mf].y) + psA);
            } else {
                psB = r01 * u2h(swR[mf].x) + (r23 * u2h(swR[mf].y) + psB);
            }
        }
        float part = (float)psA[0] + (float)psA[1] + (float)psB[0] + (float)psB[1];
        part += __shfl_xor(part, 16);
        part += __shfl_xor(part, 32);
        float sc = part + sb2v;
        if (h4 == 0) scoreRow[j0 + ln] = sc;

        // ---- unshifted exp accumulate (a = exp(sc); no max tracking) ----
        float a = expf(sc);
        s_run += a;
        {
            f16 ah = (f16)a;
            f16x2 A2 = {ah, ah};
#pragma unroll
            for (int kc = 0; kc < 4; ++kc) {
                union { f16x8 v; uint4 u; } bc; bc.v = bF_hold[kc];
                accPh[kc * 4 + 0] = x2u(u2h(bc.u.x) * A2 + u2h(accPh[kc * 4 + 0]));
                accPh[kc * 4 + 1] = x2u(u2h(bc.u.y) * A2 + u2h(accPh[kc * 4 + 1]));
                accPh[kc * 4 + 2] = x2u(u2h(bc.u.z) * A2 + u2h(accPh[kc * 4 + 2]));
                accPh[kc * 4 + 3] = x2u(u2h(bc.u.w) * A2 + u2h(accPh[kc * 4 + 3]));
            }
        }
    }

    // ---- unpack accH to fp32 ----
    float accH[4][8];
#pragma unroll
    for (int kc = 0; kc < 4; ++kc)
#pragma unroll
        for (int p = 0; p < 4; ++p) {
            f16x2 v = u2h(accPh[kc * 4 + p]);
            accH[kc][2 * p] = (float)v[0];
            accH[kc][2 * p + 1] = (float)v[1];
        }

    // ---- epilogue: plain tree sums over ln bits ----
#pragma unroll
    for (int d = 1; d < 16; d <<= 1) {
        s_run += __shfl_xor(s_run, d);
#pragma unroll
        for (int kc = 0; kc < 4; ++kc)
#pragma unroll
            for (int e = 0; e < 8; ++e) accH[kc][e] += __shfl_xor(accH[kc][e], d);
    }
    if (lane == 0) rowsum[b * N_ + i] = s_run;

    // ---- accH @ vW2 (fp32, LDS): lane (ln,h4) dims d=kc*32+h4*8+e -> f=ln*4..+3 ----
    float xp0 = 0.f, xp1 = 0.f, xp2 = 0.f, xp3 = 0.f;
#pragma unroll
    for (int kc = 0; kc < 4; ++kc) {
#pragma unroll
        for (int e = 0; e < 8; ++e) {
            int dIdx = kc * 32 + h4 * 8 + e;
            float av = accH[kc][e];
            float4 wv = *(const float4*)(smem + VW2_OFF + dIdx * 256 + ln * 16);
            xp0 = fmaf(av, wv.x, xp0); xp1 = fmaf(av, wv.y, xp1);
            xp2 = fmaf(av, wv.z, xp2); xp3 = fmaf(av, wv.w, xp3);
        }
    }
    xp0 += __shfl_xor(xp0, 16); xp0 += __shfl_xor(xp0, 32);
    xp1 += __shfl_xor(xp1, 16); xp1 += __shfl_xor(xp1, 32);
    xp2 += __shfl_xor(xp2, 16); xp2 += __shfl_xor(xp2, 32);
    xp3 += __shfl_xor(xp3, 16); xp3 += __shfl_xor(xp3, 32);
    if (h4 == 0) {
        float4 o = {xp0, xp1, xp2, xp3};
        *(float4*)(xpart + (size_t)(b * N_ + i) * F_ + ln * 4) = o;
    }
}

// -------------------- per-batch softmax total: invT[b] = 1 / sum_i rowsum_i ----------
__global__ void k_gred(const float* __restrict__ rowsum, float* __restrict__ invT) {
    int b = blockIdx.x, tid = threadIdx.x;   // 512
    __shared__ float sred[512];
    float s = (tid < N_) ? rowsum[b * N_ + tid] : 0.f;
    sred[tid] = s;
    __syncthreads();
    for (int st = 256; st > 0; st >>= 1) {
        if (tid < st) sred[tid] += sred[tid + st];
        __syncthreads();
    }
    if (tid == 0) invT[b] = 1.f / sred[0];
}

// -------------------- k_xlite: att normalize + accI + final combine --------------------
// att = exp(sc)*invT; x = 0.5*(xpart*invT + s*vb2) + 0.25*(s*in_i + att@inp),
// s = rowsum*invT
__global__ __launch_bounds__(256) void k_xlite(
    const float* __restrict__ inp, const float* __restrict__ vb2,
    float* __restrict__ scoresAtt, const float* __restrict__ rowsum,
    const float* __restrict__ invT, const float* __restrict__ xpart,
    float* __restrict__ xout) {
    int i = blockIdx.x, b = blockIdx.y;
    int tid = threadIdx.x;
    __shared__ float aLds[N_];
    __shared__ float accIp[256];

    const float invTb = invT[b];
    float* scoreRow = scoresAtt + (size_t)(b * N_ + i) * N_;

    {
        float sc = scoreRow[tid];
        float a = expf(sc) * invTb;
        scoreRow[tid] = a; aLds[tid] = a;
        if (tid < N_ - 256) {
            float sc2 = scoreRow[tid + 256];
            float a2 = expf(sc2) * invTb;
            scoreRow[tid + 256] = a2; aLds[tid + 256] = a2;
        }
    }
    __syncthreads();

    int f = tid & 63, q = tid >> 6;
    float aI = 0.f;
    const float* inB = inp + (size_t)b * N_ * F_;
    for (int j = q * 96; j < q * 96 + 96; ++j)
        aI = fmaf(aLds[j], inB[j * F_ + f], aI);
    accIp[tid] = aI;
    __syncthreads();

    if (tid < F_) {
        float accI = accIp[tid] + accIp[64 + tid] + accIp[128 + tid] + accIp[192 + tid];
        float s = rowsum[b * N_ + i] * invTb;
        float xp = xpart[(size_t)(b * N_ + i) * F_ + tid] * invTb;
        float r = 0.5f * (xp + s * vb2[tid]) +
                  0.25f * (s * inB[(size_t)i * F_ + tid] + accI);
        xout[(size_t)(b * N_ + i) * F_ + tid] = r;
    }
}

// -------------------- launch --------------------

extern "C" void kernel_launch(void* const* d_in, const int* in_sizes, int n_in,
                              void* d_out, int out_size, void* d_ws, size_t ws_size,
                              hipStream_t stream) {
    const float* inp   = (const float*)d_in[0];
    const float* pos   = (const float*)d_in[1];
    const float* vW1   = (const float*)d_in[2];
    const float* vb1   = (const float*)d_in[3];
    const float* vg    = (const float*)d_in[4];
    const float* vbeta = (const float*)d_in[5];
    const float* vW2   = (const float*)d_in[6];
    const float* vb2   = (const float*)d_in[7];
    const float* sW1   = (const float*)d_in[8];
    const float* sb1   = (const float*)d_in[9];
    const float* sW2   = (const float*)d_in[10];
    const float* sb2   = (const float*)d_in[11];

    float* xout   = (float*)d_out;                 // B*N*F
    float* attout = xout + B_ * N_ * F_;           // B*N*N (scores -> att in place)

    unsigned short* W2hT   = (unsigned short*)d_ws;                  // 32KB fp16
    unsigned int*   coeffP = (unsigned int*)((char*)d_ws + 32768);   // 1KB packed f16x2
    float*          scal   = (float*)((char*)d_ws + 33792);          // 6 scalars (pad)
    unsigned int*   sw16   = (unsigned int*)((char*)d_ws + 34048);   // 64 uints (256B)
    unsigned int*   t16    = (unsigned int*)((char*)d_ws + 34304);   // B*N*64 uints (768KB)
    float* rowsum   = (float*)((char*)d_ws + 34304 + B_ * N_ * 64 * 4);
    float* invT     = rowsum + B_ * N_;            // B floats
    float* xpart    = invT + B_;                   // B*N*64 fp32 (768KB)

    k_prep<<<B_ * N_ + 128 + 1, 128, 0, stream>>>(
        inp, sW1, vb2, sb1, vW2, vW1, vb1, vg, vbeta, sW2,
        t16, W2hT, coeffP, scal, sw16);
    k_scores<<<dim3(96, B_), 256, 0, stream>>>(
        pos, coeffP, scal, W2hT, vW2, t16, sw16, sb2, attout, rowsum, xpart);
    k_gred<<<B_, 512, 0, stream>>>(rowsum, invT);
    k_xlite<<<dim3(N_, B_), 256, 0, stream>>>(inp, vb2, attout, rowsum, invT,
                                              xpart, xout);
}

// Round 21
// 121.199 us; speedup vs baseline: 6.4210x; 1.0240x over previous
//
#include <hip/hip_runtime.h>
#include <hip/hip_bf16.h>
#include <math.h>

#define B_ 8
#define N_ 384
#define F_ 64
#define H_ 128
#define LN_EPS 1e-5f

typedef _Float16 f16;
typedef f16 f16x2 __attribute__((ext_vector_type(2)));
typedef f16 f16x4 __attribute__((ext_vector_type(4)));
typedef f16 f16x8 __attribute__((ext_vector_type(8)));
typedef float f32x4v __attribute__((ext_vector_type(4)));

static __device__ __forceinline__ f16x2 u2h(unsigned int u) {
    union { unsigned int u; f16x2 h; } c; c.u = u; return c.h;
}
static __device__ __forceinline__ unsigned int h2u(f16 a, f16 b) {
    union { f16x2 h; unsigned int u; } c; c.h = (f16x2){a, b}; return c.u;
}
static __device__ __forceinline__ unsigned int x2u(f16x2 h) {
    union { f16x2 h; unsigned int u; } c; c.h = h; return c.u;
}
// packed f32->f16x2 (round-toward-zero packer, single VALU op)
static __device__ __forceinline__ f16x2 pk2(float a, float b) {
    auto r = __builtin_amdgcn_cvt_pkrtz(a, b);
    union { decltype(r) r; f16x2 h; } c; c.r = r; return c.h;
}

// packed-permuted index helpers: uint slot u = h4*16 + mf*2 + p packs
// elements (n, n+1) with n = mf*16 + h4*4 + 2p  (matches MFMA C/D row layout)
static __device__ __forceinline__ void perm_idx(int m, int& u, int& n0) {
    int h4 = (m >> 1) & 3, mf = m >> 3, p = m & 1;
    u = h4 * 16 + mf * 2 + p;
    n0 = mf * 16 + h4 * 4 + 2 * p;
}

// -------------------- fused setup kernel --------------------
__global__ __launch_bounds__(128) void k_prep(
    const float* __restrict__ inp, const float* __restrict__ sW1,
    const float* __restrict__ vb2, const float* __restrict__ sb1,
    const float* __restrict__ vW2, const float* __restrict__ vW1,
    const float* __restrict__ vb1, const float* __restrict__ vg,
    const float* __restrict__ vbeta, const float* __restrict__ sW2,
    unsigned int* __restrict__ t16, unsigned short* __restrict__ W2hT,
    unsigned int* __restrict__ coeffP, float* __restrict__ scal,
    unsigned int* __restrict__ sw16) {
    __shared__ float red[128];
    __shared__ float caS[128], cbS[128], ccS[128];
    const int bx = blockIdx.x;
    const int tid = threadIdx.x;

    if (bx < B_ * N_) {
        // tt[n] = 0.25*(in[row]+vb2)@sW1[:,n] + 0.5*sb1[n] ; pack-permute to t16
        int row = bx, n = tid;
        float acc = 0.f;
#pragma unroll
        for (int f = 0; f < F_; ++f)
            acc = fmaf(0.25f * (inp[row * F_ + f] + vb2[f]), sW1[f * H_ + n], acc);
        red[n] = acc + 0.5f * sb1[n];
        __syncthreads();
        if (tid < 64) {
            int u, n0; perm_idx(tid, u, n0);
            t16[row * 64 + u] = h2u((f16)red[n0], (f16)red[n0 + 1]);
        }
        return;
    }
    if (bx < B_ * N_ + 128) {
        int idx = (bx - B_ * N_) * 128 + tid;
        int k = idx >> 7, n = idx & 127;
        float acc = 0.f;
#pragma unroll
        for (int f = 0; f < F_; ++f) acc = fmaf(vW2[k * F_ + f], sW1[f * H_ + n], acc);
        f16 hv = (f16)(0.5f * acc);
        W2hT[n * H_ + k] = *reinterpret_cast<unsigned short*>(&hv);
        return;
    }

    // ---- algebraic-LN coefficients + sw16 ----
    const int d = tid;   // 128
    float a = vW1[d], bb = vW1[H_ + d], c = vb1[d];
    float mA, mB, mC, Saa, Sbb, Scc, Sab, Sac, Sbc;
    float ca, cb, cc;
#define BMEAN(OUT, VAL)                                                  \
    red[d] = (VAL); __syncthreads();                                     \
    for (int st = 64; st > 0; st >>= 1) {                                \
        if (d < st) red[d] += red[d + st];                               \
        __syncthreads();                                                 \
    }                                                                    \
    OUT = red[0] * (1.f / 128.f); __syncthreads();

    BMEAN(mA, a); BMEAN(mB, bb); BMEAN(mC, c);
    ca = a - mA; cb = bb - mB; cc = c - mC;
    caS[d] = ca * vg[d]; cbS[d] = cb * vg[d]; ccS[d] = cc * vg[d];
    BMEAN(Saa, ca * ca); BMEAN(Sbb, cb * cb); BMEAN(Scc, cc * cc);
    BMEAN(Sab, ca * cb); BMEAN(Sac, ca * cc); BMEAN(Sbc, cb * cc);
#undef BMEAN
    __syncthreads();
    if (d < 64) {
        int d0 = 2 * d;
        coeffP[d]       = h2u((f16)caS[d0], (f16)caS[d0 + 1]);
        coeffP[64 + d]  = h2u((f16)cbS[d0], (f16)cbS[d0 + 1]);
        coeffP[128 + d] = h2u((f16)ccS[d0], (f16)ccS[d0 + 1]);
        coeffP[192 + d] = h2u((f16)vbeta[d0], (f16)vbeta[d0 + 1]);
        int u, n0; perm_idx(d, u, n0);
        sw16[u] = h2u((f16)sW2[n0], (f16)sW2[n0 + 1]);
    }
    if (d == 0) {
        scal[0] = Saa; scal[1] = Sbb; scal[2] = Scc;
        scal[3] = Sab; scal[4] = Sac; scal[5] = Sbc;
    }
}

// -------------------- phase 1: scores + unshifted-exp accH (VALU trim v2) --------------------
// R20 base. NEW: (1) acc-init folded into kc=0 MFMA (C = acc0 directly; -32 movs/tile);
// (2) 2-tile ping-pong (bFA/bFB alternate; kills bF_hold/bF_cur copies, -32 movs/tile);
// (3) __expf fast path. No launch-bound min-waves arg (R5/R6/R16 spill rule).
#define VW2_OFF 32768
__global__ __launch_bounds__(256) void k_scores(
    const float* __restrict__ pos, const unsigned int* __restrict__ coeffP,
    const float* __restrict__ scal, const unsigned short* __restrict__ W2hT,
    const float* __restrict__ vW2, const unsigned int* __restrict__ t16,
    const unsigned int* __restrict__ sw16, const float* __restrict__ sb2,
    float* __restrict__ scores, float* __restrict__ rowsum,
    float* __restrict__ xpart) {
    __shared__ __align__(16) char smem[65536];   // 32KB W' (swizzled) + 32KB vW2 fp32

    const int tid = threadIdx.x;
    const int b = blockIdx.y;
    const int w = tid >> 6, lane = tid & 63;
    const int i = blockIdx.x * 4 + w;
    const int ln = lane & 15, h4 = lane >> 4;

    // ---- one-time stage: W' swizzled + vW2 fp32 ----
#pragma unroll
    for (int s = 0; s < 8; ++s) {
        int idx = tid + s * 256;
        int n = idx >> 4, c = idx & 15;
        uint4 v = *(const uint4*)(W2hT + n * H_ + c * 8);
        *(uint4*)(smem + ((n * 256 + c * 16) ^ ((n & 7) << 4))) = v;
    }
#pragma unroll
    for (int s = 0; s < 8; ++s) {
        int idx = tid + s * 256;            // 0..2047 float4 chunks of vW2 (128x64)
        uint4 v = *(const uint4*)((const float*)vW2 + idx * 4);
        *(uint4*)(smem + VW2_OFF + idx * 16) = v;
    }
    __syncthreads();

    // ---- resident state ----
    uint4 cagR[4], cbgR[4], ccgR[4], vbR[4];
#pragma unroll
    for (int kc = 0; kc < 4; ++kc) {
        cagR[kc] = *(const uint4*)(coeffP + kc * 16 + h4 * 4);
        cbgR[kc] = *(const uint4*)(coeffP + 64 + kc * 16 + h4 * 4);
        ccgR[kc] = *(const uint4*)(coeffP + 128 + kc * 16 + h4 * 4);
        vbR[kc]  = *(const uint4*)(coeffP + 192 + kc * 16 + h4 * 4);
    }
    // acc-init (= ti) resident in fp32 — consumed as the kc=0 MFMA C operand
    f32x4v acc0[8];
    {
        const unsigned int* tiP = t16 + (size_t)(b * N_ + i) * 64 + h4 * 16;
#pragma unroll
        for (int s = 0; s < 4; ++s) {
            uint4 v = *(const uint4*)(tiP + s * 4);
            f16x2 a0 = u2h(v.x), a1 = u2h(v.y), a2 = u2h(v.z), a3 = u2h(v.w);
            acc0[s * 2][0] = (float)a0[0]; acc0[s * 2][1] = (float)a0[1];
            acc0[s * 2][2] = (float)a1[0]; acc0[s * 2][3] = (float)a1[1];
            acc0[s * 2 + 1][0] = (float)a2[0]; acc0[s * 2 + 1][1] = (float)a2[1];
            acc0[s * 2 + 1][2] = (float)a3[0]; acc0[s * 2 + 1][3] = (float)a3[1];
        }
    }
    uint2 swR[8];
#pragma unroll
    for (int mf = 0; mf < 8; ++mf)
        swR[mf] = *(const uint2*)(sw16 + h4 * 16 + mf * 2);

    const float Saa = scal[0], Sbb = scal[1], Scc = scal[2];
    const float Sab = scal[3], Sac = scal[4], Sbc = scal[5];
    const float sb2v = sb2[0];

    const float* pi = pos + (size_t)(b * N_ + i) * 3;
    const float ax = pi[0], ay = pi[1], az = pi[2];
    float* scoreRow = scores + (size_t)(b * N_ + i) * N_;

    float s_run = 0.f;
    unsigned int accPh[16];                    // packed f16x2 accH (kc*4 + e/2)
#pragma unroll
    for (int k = 0; k < 16; ++k) accPh[k] = 0u;

    // bF construction from a given j-pos (uses resident coeffs)
    auto makeBF = [&](float bx_, float by_, float bz_, f16x8 (&bF)[4]) {
        float dotv = ax * bx_ + ay * by_ + az * bz_;
        float cx = ay * bz_ - az * by_;
        float cy = az * bx_ - ax * bz_;
        float cz = ax * by_ - ay * bx_;
        float cns = cx * cx + cy * cy + cz * cz;
        float cn = sqrtf(cns);
        float var = Saa * dotv * dotv + Sbb * cns + Scc +
                    2.f * (Sab * dotv * cn + Sac * dotv + Sbc * cn);
        float rstd = rsqrtf(var + LN_EPS);
        f16 d2 = (f16)(dotv * rstd), c2 = (f16)(cn * rstd), r2 = (f16)rstd;
        f16x2 D2 = {d2, d2}, C2 = {c2, c2}, R2 = {r2, r2};
        const f16x2 Z = {(f16)0.f, (f16)0.f};
#pragma unroll
        for (int kc = 0; kc < 4; ++kc) {
            f16x2 vp0 = __builtin_elementwise_max(D2 * u2h(cagR[kc].x) + (C2 * u2h(cbgR[kc].x) + (R2 * u2h(ccgR[kc].x) + u2h(vbR[kc].x))), Z);
            f16x2 vp1 = __builtin_elementwise_max(D2 * u2h(cagR[kc].y) + (C2 * u2h(cbgR[kc].y) + (R2 * u2h(ccgR[kc].y) + u2h(vbR[kc].y))), Z);
            f16x2 vp2 = __builtin_elementwise_max(D2 * u2h(cagR[kc].z) + (C2 * u2h(cbgR[kc].z) + (R2 * u2h(ccgR[kc].z) + u2h(vbR[kc].z))), Z);
            f16x2 vp3 = __builtin_elementwise_max(D2 * u2h(cagR[kc].w) + (C2 * u2h(cbgR[kc].w) + (R2 * u2h(ccgR[kc].w) + u2h(vbR[kc].w))), Z);
            f16x4 q01 = __builtin_shufflevector(vp0, vp1, 0, 1, 2, 3);
            f16x4 q23 = __builtin_shufflevector(vp2, vp3, 0, 1, 2, 3);
            bF[kc] = __builtin_shufflevector(q01, q23, 0, 1, 2, 3, 4, 5, 6, 7);
        }
    };

    // per-tile body: GEMM with bFu (kc0 C=acc0), build bFb for tile jt+1,
    // pos prefetch for jt+2, phaseC, exp+accH with bFu.
    float bx, by, bz;
    auto body = [&](int jt, f16x8 (&bFu)[4], f16x8 (&bFb)[4]) {
        const int j0 = jt * 16;

        // tj prefetch (packed), consumed at phaseC
        const unsigned int* tjP = t16 + (size_t)(b * N_ + j0 + ln) * 64 + h4 * 16;
        uint4 tj0 = *(const uint4*)(tjP);
        uint4 tj1 = *(const uint4*)(tjP + 4);
        uint4 tj2 = *(const uint4*)(tjP + 8);
        uint4 tj3 = *(const uint4*)(tjP + 12);

        // GEMM: kc=0 uses acc0 as C (free init); kc=1..3 accumulate
        f32x4v acc[8];
        {
            const int kb = (h4 * 16) ^ ((ln & 7) << 4);
#pragma unroll
            for (int mf = 0; mf < 8; ++mf) {
                f16x8 aFr = *(const f16x8*)(smem + (mf * 16 + ln) * 256 + kb);
                acc[mf] = __builtin_amdgcn_mfma_f32_16x16x32_f16(aFr, bFu[0], acc0[mf], 0, 0, 0);
            }
        }
#pragma unroll
        for (int kc = 1; kc < 4; ++kc) {
            const int kb = (kc * 64 + h4 * 16) ^ ((ln & 7) << 4);
#pragma unroll
            for (int mf = 0; mf < 8; ++mf) {
                f16x8 aFr = *(const f16x8*)(smem + (mf * 16 + ln) * 256 + kb);
                acc[mf] = __builtin_amdgcn_mfma_f32_16x16x32_f16(aFr, bFu[kc], acc[mf], 0, 0, 0);
            }
        }

        // build NEXT tile's bF while MFMAs drain (independent VALU)
        {
            float gx = bx, gy = by, gz = bz;
            int jn2 = (jt + 2 < 24) ? (jt + 2) : 23;
            const float* pn = pos + (size_t)(b * N_ + jn2 * 16 + ln) * 3;
            bx = pn[0]; by = pn[1]; bz = pn[2];
            makeBF(gx, gy, gz, bFb);
        }

        // phaseC (packed fp16): relu(acc+tj) dot sw; reduce over h4
        unsigned int tju[16] = {tj0.x, tj0.y, tj0.z, tj0.w, tj1.x, tj1.y, tj1.z, tj1.w,
                                tj2.x, tj2.y, tj2.z, tj2.w, tj3.x, tj3.y, tj3.z, tj3.w};
        const f16x2 Z = {(f16)0.f, (f16)0.f};
        f16x2 psA = Z, psB = Z;
#pragma unroll
        for (int mf = 0; mf < 8; ++mf) {
            f16x2 p01 = pk2(acc[mf][0], acc[mf][1]);
            f16x2 p23 = pk2(acc[mf][2], acc[mf][3]);
            f16x2 r01 = __builtin_elementwise_max(p01 + u2h(tju[mf * 2]), Z);
            f16x2 r23 = __builtin_elementwise_max(p23 + u2h(tju[mf * 2 + 1]), Z);
            if (mf < 4) {
                psA = r01 * u2h(swR[mf].x) + (r23 * u2h(swR[mf].y) + psA);
            } else {
                psB = r01 * u2h(swR[mf].x) + (r23 * u2h(swR[mf].y) + psB);
            }
        }
        f16x2 ps = psA + psB;
        float part = (float)ps[0] + (float)ps[1];
        part += __shfl_xor(part, 16);
        part += __shfl_xor(part, 32);
        float sc = part + sb2v;
        if (h4 == 0) scoreRow[j0 + ln] = sc;

        // unshifted exp accumulate
        float a = __expf(sc);
        s_run += a;
        {
            f16 ah = (f16)a;
            f16x2 A2 = {ah, ah};
#pragma unroll
            for (int kc = 0; kc < 4; ++kc) {
                union { f16x8 v; uint4 u; } bc; bc.v = bFu[kc];
                accPh[kc * 4 + 0] = x2u(u2h(bc.u.x) * A2 + u2h(accPh[kc * 4 + 0]));
                accPh[kc * 4 + 1] = x2u(u2h(bc.u.y) * A2 + u2h(accPh[kc * 4 + 1]));
                accPh[kc * 4 + 2] = x2u(u2h(bc.u.z) * A2 + u2h(accPh[kc * 4 + 2]));
                accPh[kc * 4 + 3] = x2u(u2h(bc.u.w) * A2 + u2h(accPh[kc * 4 + 3]));
            }
        }
    };

    // ---- prologue: bFA for tile 0; pos prefetch for tile 1 ----
    f16x8 bFA[4], bFB[4];
    {
        const float* p0 = pos + (size_t)(b * N_ + ln) * 3;
        bx = p0[0]; by = p0[1]; bz = p0[2];
    }
    makeBF(bx, by, bz, bFA);
    {
        const float* p1 = pos + (size_t)(b * N_ + 16 + ln) * 3;
        bx = p1[0]; by = p1[1]; bz = p1[2];
    }

#pragma unroll 1
    for (int t = 0; t < 12; ++t) {
        body(2 * t, bFA, bFB);
        body(2 * t + 1, bFB, bFA);
    }

    // ---- unpack accH to fp32 ----
    float accH[4][8];
#pragma unroll
    for (int kc = 0; kc < 4; ++kc)
#pragma unroll
        for (int p = 0; p < 4; ++p) {
            f16x2 v = u2h(accPh[kc * 4 + p]);
            accH[kc][2 * p] = (float)v[0];
            accH[kc][2 * p + 1] = (float)v[1];
        }

    // ---- epilogue: plain tree sums over ln bits ----
#pragma unroll
    for (int d = 1; d < 16; d <<= 1) {
        s_run += __shfl_xor(s_run, d);
#pragma unroll
        for (int kc = 0; kc < 4; ++kc)
#pragma unroll
            for (int e = 0; e < 8; ++e) accH[kc][e] += __shfl_xor(accH[kc][e], d);
    }
    if (lane == 0) rowsum[b * N_ + i] = s_run;

    // ---- accH @ vW2 (fp32, LDS): lane (ln,h4) dims d=kc*32+h4*8+e -> f=ln*4..+3 ----
    float xp0 = 0.f, xp1 = 0.f, xp2 = 0.f, xp3 = 0.f;
#pragma unroll
    for (int kc = 0; kc < 4; ++kc) {
#pragma unroll
        for (int e = 0; e < 8; ++e) {
            int dIdx = kc * 32 + h4 * 8 + e;
            float av = accH[kc][e];
            float4 wv = *(const float4*)(smem + VW2_OFF + dIdx * 256 + ln * 16);
            xp0 = fmaf(av, wv.x, xp0); xp1 = fmaf(av, wv.y, xp1);
            xp2 = fmaf(av, wv.z, xp2); xp3 = fmaf(av, wv.w, xp3);
        }
    }
    xp0 += __shfl_xor(xp0, 16); xp0 += __shfl_xor(xp0, 32);
    xp1 += __shfl_xor(xp1, 16); xp1 += __shfl_xor(xp1, 32);
    xp2 += __shfl_xor(xp2, 16); xp2 += __shfl_xor(xp2, 32);
    xp3 += __shfl_xor(xp3, 16); xp3 += __shfl_xor(xp3, 32);
    if (h4 == 0) {
        float4 o = {xp0, xp1, xp2, xp3};
        *(float4*)(xpart + (size_t)(b * N_ + i) * F_ + ln * 4) = o;
    }
}

// -------------------- per-batch softmax total: invT[b] = 1 / sum_i rowsum_i ----------
__global__ void k_gred(const float* __restrict__ rowsum, float* __restrict__ invT) {
    int b = blockIdx.x, tid = threadIdx.x;   // 512
    __shared__ float sred[512];
    float s = (tid < N_) ? rowsum[b * N_ + tid] : 0.f;
    sred[tid] = s;
    __syncthreads();
    for (int st = 256; st > 0; st >>= 1) {
        if (tid < st) sred[tid] += sred[tid + st];
        __syncthreads();
    }
    if (tid == 0) invT[b] = 1.f / sred[0];
}

// -------------------- k_xlite: att normalize + accI + final combine --------------------
// att = exp(sc)*invT; x = 0.5*(xpart*invT + s*vb2) + 0.25*(s*in_i + att@inp),
// s = rowsum*invT
__global__ __launch_bounds__(256) void k_xlite(
    const float* __restrict__ inp, const float* __restrict__ vb2,
    float* __restrict__ scoresAtt, const float* __restrict__ rowsum,
    const float* __restrict__ invT, const float* __restrict__ xpart,
    float* __restrict__ xout) {
    int i = blockIdx.x, b = blockIdx.y;
    int tid = threadIdx.x;
    __shared__ float aLds[N_];
    __shared__ float accIp[256];

    const float invTb = invT[b];
    float* scoreRow = scoresAtt + (size_t)(b * N_ + i) * N_;

    {
        float sc = scoreRow[tid];
        float a = __expf(sc) * invTb;
        scoreRow[tid] = a; aLds[tid] = a;
        if (tid < N_ - 256) {
            float sc2 = scoreRow[tid + 256];
            float a2 = __expf(sc2) * invTb;
            scoreRow[tid + 256] = a2; aLds[tid + 256] = a2;
        }
    }
    __syncthreads();

    int f = tid & 63, q = tid >> 6;
    float aI = 0.f;
    const float* inB = inp + (size_t)b * N_ * F_;
    for (int j = q * 96; j < q * 96 + 96; ++j)
        aI = fmaf(aLds[j], inB[j * F_ + f], aI);
    accIp[tid] = aI;
    __syncthreads();

    if (tid < F_) {
        float accI = accIp[tid] + accIp[64 + tid] + accIp[128 + tid] + accIp[192 + tid];
        float s = rowsum[b * N_ + i] * invTb;
        float xp = xpart[(size_t)(b * N_ + i) * F_ + tid] * invTb;
        float r = 0.5f * (xp + s * vb2[tid]) +
                  0.25f * (s * inB[(size_t)i * F_ + tid] + accI);
        xout[(size_t)(b * N_ + i) * F_ + tid] = r;
    }
}

// -------------------- launch --------------------

extern "C" void kernel_launch(void* const* d_in, const int* in_sizes, int n_in,
                              void* d_out, int out_size, void* d_ws, size_t ws_size,
                              hipStream_t stream) {
    const float* inp   = (const float*)d_in[0];
    const float* pos   = (const float*)d_in[1];
    const float* vW1   = (const float*)d_in[2];
    const float* vb1   = (const float*)d_in[3];
    const float* vg    = (const float*)d_in[4];
    const float* vbeta = (const float*)d_in[5];
    const float* vW2   = (const float*)d_in[6];
    const float* vb2   = (const float*)d_in[7];
    const float* sW1   = (const float*)d_in[8];
    const float* sb1   = (const float*)d_in[9];
    const float* sW2   = (const float*)d_in[10];
    const float* sb2   = (const float*)d_in[11];

    float* xout   = (float*)d_out;                 // B*N*F
    float* attout = xout + B_ * N_ * F_;           // B*N*N (scores -> att in place)

    unsigned short* W2hT   = (unsigned short*)d_ws;                  // 32KB fp16
    unsigned int*   coeffP = (unsigned int*)((char*)d_ws + 32768);   // 1KB packed f16x2
    float*          scal   = (float*)((char*)d_ws + 33792);          // 6 scalars (pad)
    unsigned int*   sw16   = (unsigned int*)((char*)d_ws + 34048);   // 64 uints (256B)
    unsigned int*   t16    = (unsigned int*)((char*)d_ws + 34304);   // B*N*64 uints (768KB)
    float* rowsum   = (float*)((char*)d_ws + 34304 + B_ * N_ * 64 * 4);
    float* invT     = rowsum + B_ * N_;            // B floats
    float* xpart    = invT + B_;                   // B*N*64 fp32 (768KB)

    k_prep<<<B_ * N_ + 128 + 1, 128, 0, stream>>>(
        inp, sW1, vb2, sb1, vW2, vW1, vb1, vg, vbeta, sW2,
        t16, W2hT, coeffP, scal, sw16);
    k_scores<<<dim3(96, B_), 256, 0, stream>>>(
        pos, coeffP, scal, W2hT, vW2, t16, sw16, sb2, attout, rowsum, xpart);
    k_gred<<<B_, 512, 0, stream>>>(rowsum, invT);
    k_xlite<<<dim3(N_, B_), 256, 0, stream>>>(inp, vb2, attout, rowsum, invT,
                                              xpart, xout);
}

// Round 22
// 109.348 us; speedup vs baseline: 7.1169x; 1.1084x over previous
//
#include <hip/hip_runtime.h>
#include <hip/hip_bf16.h>
#include <math.h>

#define B_ 8
#define N_ 384
#define F_ 64
#define H_ 128
#define LN_EPS 1e-5f

typedef _Float16 f16;
typedef f16 f16x2 __attribute__((ext_vector_type(2)));
typedef f16 f16x4 __attribute__((ext_vector_type(4)));
typedef f16 f16x8 __attribute__((ext_vector_type(8)));
typedef float f32x4v __attribute__((ext_vector_type(4)));

static __device__ __forceinline__ f16x2 u2h(unsigned int u) {
    union { unsigned int u; f16x2 h; } c; c.u = u; return c.h;
}
static __device__ __forceinline__ unsigned int h2u(f16 a, f16 b) {
    union { f16x2 h; unsigned int u; } c; c.h = (f16x2){a, b}; return c.u;
}
static __device__ __forceinline__ unsigned int x2u(f16x2 h) {
    union { f16x2 h; unsigned int u; } c; c.h = h; return c.u;
}
// packed f32->f16x2 (round-toward-zero packer, single VALU op)
static __device__ __forceinline__ f16x2 pk2(float a, float b) {
    auto r = __builtin_amdgcn_cvt_pkrtz(a, b);
    union { decltype(r) r; f16x2 h; } c; c.r = r; return c.h;
}

// packed-permuted index helpers: uint slot u = h4*16 + mf*2 + p packs
// elements (n, n+1) with n = mf*16 + h4*4 + 2p  (matches MFMA C/D row layout)
static __device__ __forceinline__ void perm_idx(int m, int& u, int& n0) {
    int h4 = (m >> 1) & 3, mf = m >> 3, p = m & 1;
    u = h4 * 16 + mf * 2 + p;
    n0 = mf * 16 + h4 * 4 + 2 * p;
}

// -------------------- fused setup kernel --------------------
__global__ __launch_bounds__(128) void k_prep(
    const float* __restrict__ inp, const float* __restrict__ sW1,
    const float* __restrict__ vb2, const float* __restrict__ sb1,
    const float* __restrict__ vW2, const float* __restrict__ vW1,
    const float* __restrict__ vb1, const float* __restrict__ vg,
    const float* __restrict__ vbeta, const float* __restrict__ sW2,
    unsigned int* __restrict__ t16, unsigned short* __restrict__ W2hT,
    unsigned int* __restrict__ coeffP, float* __restrict__ scal,
    unsigned int* __restrict__ sw16) {
    __shared__ float red[128];
    __shared__ float caS[128], cbS[128], ccS[128];
    const int bx = blockIdx.x;
    const int tid = threadIdx.x;

    if (bx < B_ * N_) {
        // tt[n] = 0.25*(in[row]+vb2)@sW1[:,n] + 0.5*sb1[n] ; pack-permute to t16
        int row = bx, n = tid;
        float acc = 0.f;
#pragma unroll
        for (int f = 0; f < F_; ++f)
            acc = fmaf(0.25f * (inp[row * F_ + f] + vb2[f]), sW1[f * H_ + n], acc);
        red[n] = acc + 0.5f * sb1[n];
        __syncthreads();
        if (tid < 64) {
            int u, n0; perm_idx(tid, u, n0);
            t16[row * 64 + u] = h2u((f16)red[n0], (f16)red[n0 + 1]);
        }
        return;
    }
    if (bx < B_ * N_ + 128) {
        int idx = (bx - B_ * N_) * 128 + tid;
        int k = idx >> 7, n = idx & 127;
        float acc = 0.f;
#pragma unroll
        for (int f = 0; f < F_; ++f) acc = fmaf(vW2[k * F_ + f], sW1[f * H_ + n], acc);
        f16 hv = (f16)(0.5f * acc);
        W2hT[n * H_ + k] = *reinterpret_cast<unsigned short*>(&hv);
        return;
    }

    // ---- algebraic-LN coefficients + sw16 ----
    const int d = tid;   // 128
    float a = vW1[d], bb = vW1[H_ + d], c = vb1[d];
    float mA, mB, mC, Saa, Sbb, Scc, Sab, Sac, Sbc;
    float ca, cb, cc;
#define BMEAN(OUT, VAL)                                                  \
    red[d] = (VAL); __syncthreads();                                     \
    for (int st = 64; st > 0; st >>= 1) {                                \
        if (d < st) red[d] += red[d + st];                               \
        __syncthreads();                                                 \
    }                                                                    \
    OUT = red[0] * (1.f / 128.f); __syncthreads();

    BMEAN(mA, a); BMEAN(mB, bb); BMEAN(mC, c);
    ca = a - mA; cb = bb - mB; cc = c - mC;
    caS[d] = ca * vg[d]; cbS[d] = cb * vg[d]; ccS[d] = cc * vg[d];
    BMEAN(Saa, ca * ca); BMEAN(Sbb, cb * cb); BMEAN(Scc, cc * cc);
    BMEAN(Sab, ca * cb); BMEAN(Sac, ca * cc); BMEAN(Sbc, cb * cc);
#undef BMEAN
    __syncthreads();
    if (d < 64) {
        int d0 = 2 * d;
        coeffP[d]       = h2u((f16)caS[d0], (f16)caS[d0 + 1]);
        coeffP[64 + d]  = h2u((f16)cbS[d0], (f16)cbS[d0 + 1]);
        coeffP[128 + d] = h2u((f16)ccS[d0], (f16)ccS[d0 + 1]);
        coeffP[192 + d] = h2u((f16)vbeta[d0], (f16)vbeta[d0 + 1]);
        int u, n0; perm_idx(d, u, n0);
        sw16[u] = h2u((f16)sW2[n0], (f16)sW2[n0 + 1]);
    }
    if (d == 0) {
        scal[0] = Saa; scal[1] = Sbb; scal[2] = Scc;
        scal[3] = Sab; scal[4] = Sac; scal[5] = Sbc;
    }
}

// -------------------- phase 1: scores + unshifted-exp accH (setprio + hoisted addr) ------
// R21 base. NEW: (1) s_setprio(1) around the 32-MFMA cluster — barrier-free blocks put
// co-resident waves at different phases, the regime where setprio pays; (2) LDS A-read
// base hoisted to a named register (body uses base + compile-time offsets).
#define VW2_OFF 32768
__global__ __launch_bounds__(256) void k_scores(
    const float* __restrict__ pos, const unsigned int* __restrict__ coeffP,
    const float* __restrict__ scal, const unsigned short* __restrict__ W2hT,
    const float* __restrict__ vW2, const unsigned int* __restrict__ t16,
    const unsigned int* __restrict__ sw16, const float* __restrict__ sb2,
    float* __restrict__ scores, float* __restrict__ rowsum,
    float* __restrict__ xpart) {
    __shared__ __align__(16) char smem[65536];   // 32KB W' (swizzled) + 32KB vW2 fp32

    const int tid = threadIdx.x;
    const int b = blockIdx.y;
    const int w = tid >> 6, lane = tid & 63;
    const int i = blockIdx.x * 4 + w;
    const int ln = lane & 15, h4 = lane >> 4;

    // ---- one-time stage: W' swizzled + vW2 fp32 ----
#pragma unroll
    for (int s = 0; s < 8; ++s) {
        int idx = tid + s * 256;
        int n = idx >> 4, c = idx & 15;
        uint4 v = *(const uint4*)(W2hT + n * H_ + c * 8);
        *(uint4*)(smem + ((n * 256 + c * 16) ^ ((n & 7) << 4))) = v;
    }
#pragma unroll
    for (int s = 0; s < 8; ++s) {
        int idx = tid + s * 256;            // 0..2047 float4 chunks of vW2 (128x64)
        uint4 v = *(const uint4*)((const float*)vW2 + idx * 4);
        *(uint4*)(smem + VW2_OFF + idx * 16) = v;
    }
    __syncthreads();

    // ---- resident state ----
    uint4 cagR[4], cbgR[4], ccgR[4], vbR[4];
#pragma unroll
    for (int kc = 0; kc < 4; ++kc) {
        cagR[kc] = *(const uint4*)(coeffP + kc * 16 + h4 * 4);
        cbgR[kc] = *(const uint4*)(coeffP + 64 + kc * 16 + h4 * 4);
        ccgR[kc] = *(const uint4*)(coeffP + 128 + kc * 16 + h4 * 4);
        vbR[kc]  = *(const uint4*)(coeffP + 192 + kc * 16 + h4 * 4);
    }
    // acc-init (= ti) resident in fp32 — consumed as the kc=0 MFMA C operand
    f32x4v acc0[8];
    {
        const unsigned int* tiP = t16 + (size_t)(b * N_ + i) * 64 + h4 * 16;
#pragma unroll
        for (int s = 0; s < 4; ++s) {
            uint4 v = *(const uint4*)(tiP + s * 4);
            f16x2 a0 = u2h(v.x), a1 = u2h(v.y), a2 = u2h(v.z), a3 = u2h(v.w);
            acc0[s * 2][0] = (float)a0[0]; acc0[s * 2][1] = (float)a0[1];
            acc0[s * 2][2] = (float)a1[0]; acc0[s * 2][3] = (float)a1[1];
            acc0[s * 2 + 1][0] = (float)a2[0]; acc0[s * 2 + 1][1] = (float)a2[1];
            acc0[s * 2 + 1][2] = (float)a3[0]; acc0[s * 2 + 1][3] = (float)a3[1];
        }
    }
    uint2 swR[8];
#pragma unroll
    for (int mf = 0; mf < 8; ++mf)
        swR[mf] = *(const uint2*)(sw16 + h4 * 16 + mf * 2);

    const float Saa = scal[0], Sbb = scal[1], Scc = scal[2];
    const float Sab = scal[3], Sac = scal[4], Sbc = scal[5];
    const float sb2v = sb2[0];

    const float* pi = pos + (size_t)(b * N_ + i) * 3;
    const float ax = pi[0], ay = pi[1], az = pi[2];
    float* scoreRow = scores + (size_t)(b * N_ + i) * N_;

    // hoisted LDS A-read base: row ln, k-chunk h4, 8-way swizzle (loop-invariant)
    const char* aBase = smem + ln * 256 + ((h4 * 16) ^ ((ln & 7) << 4));
    // per-(mf,kc) offsets mf*4096 + (kc*64 "xor-free": kc*64 has bits>=6, swz bits 4-6,
    // but (kc*64 + h4*16)^ksw != kc*64 + (h4*16^ksw) when ksw bit6 set — so keep full calc
    // for kc>0 via a second hoisted base per kc.
    const char* aBaseK[4];
#pragma unroll
    for (int kc = 0; kc < 4; ++kc)
        aBaseK[kc] = smem + ln * 256 + ((kc * 64 + h4 * 16) ^ ((ln & 7) << 4));

    float s_run = 0.f;
    unsigned int accPh[16];                    // packed f16x2 accH (kc*4 + e/2)
#pragma unroll
    for (int k = 0; k < 16; ++k) accPh[k] = 0u;

    // bF construction from a given j-pos (uses resident coeffs)
    auto makeBF = [&](float bx_, float by_, float bz_, f16x8 (&bF)[4]) {
        float dotv = ax * bx_ + ay * by_ + az * bz_;
        float cx = ay * bz_ - az * by_;
        float cy = az * bx_ - ax * bz_;
        float cz = ax * by_ - ay * bx_;
        float cns = cx * cx + cy * cy + cz * cz;
        float cn = sqrtf(cns);
        float var = Saa * dotv * dotv + Sbb * cns + Scc +
                    2.f * (Sab * dotv * cn + Sac * dotv + Sbc * cn);
        float rstd = rsqrtf(var + LN_EPS);
        f16 d2 = (f16)(dotv * rstd), c2 = (f16)(cn * rstd), r2 = (f16)rstd;
        f16x2 D2 = {d2, d2}, C2 = {c2, c2}, R2 = {r2, r2};
        const f16x2 Z = {(f16)0.f, (f16)0.f};
#pragma unroll
        for (int kc = 0; kc < 4; ++kc) {
            f16x2 vp0 = __builtin_elementwise_max(D2 * u2h(cagR[kc].x) + (C2 * u2h(cbgR[kc].x) + (R2 * u2h(ccgR[kc].x) + u2h(vbR[kc].x))), Z);
            f16x2 vp1 = __builtin_elementwise_max(D2 * u2h(cagR[kc].y) + (C2 * u2h(cbgR[kc].y) + (R2 * u2h(ccgR[kc].y) + u2h(vbR[kc].y))), Z);
            f16x2 vp2 = __builtin_elementwise_max(D2 * u2h(cagR[kc].z) + (C2 * u2h(cbgR[kc].z) + (R2 * u2h(ccgR[kc].z) + u2h(vbR[kc].z))), Z);
            f16x2 vp3 = __builtin_elementwise_max(D2 * u2h(cagR[kc].w) + (C2 * u2h(cbgR[kc].w) + (R2 * u2h(ccgR[kc].w) + u2h(vbR[kc].w))), Z);
            f16x4 q01 = __builtin_shufflevector(vp0, vp1, 0, 1, 2, 3);
            f16x4 q23 = __builtin_shufflevector(vp2, vp3, 0, 1, 2, 3);
            bF[kc] = __builtin_shufflevector(q01, q23, 0, 1, 2, 3, 4, 5, 6, 7);
        }
    };

    // per-tile body: GEMM with bFu (kc0 C=acc0), build bFb for tile jt+1,
    // pos prefetch for jt+2, phaseC, exp+accH with bFu.
    float bx, by, bz;
    auto body = [&](int jt, f16x8 (&bFu)[4], f16x8 (&bFb)[4]) {
        const int j0 = jt * 16;

        // tj prefetch (packed), consumed at phaseC
        const unsigned int* tjP = t16 + (size_t)(b * N_ + j0 + ln) * 64 + h4 * 16;
        uint4 tj0 = *(const uint4*)(tjP);
        uint4 tj1 = *(const uint4*)(tjP + 4);
        uint4 tj2 = *(const uint4*)(tjP + 8);
        uint4 tj3 = *(const uint4*)(tjP + 12);

        // GEMM: kc=0 uses acc0 as C (free init); kc=1..3 accumulate
        __builtin_amdgcn_s_setprio(1);
        f32x4v acc[8];
#pragma unroll
        for (int mf = 0; mf < 8; ++mf) {
            f16x8 aFr = *(const f16x8*)(aBaseK[0] + mf * 4096);
            acc[mf] = __builtin_amdgcn_mfma_f32_16x16x32_f16(aFr, bFu[0], acc0[mf], 0, 0, 0);
        }
#pragma unroll
        for (int kc = 1; kc < 4; ++kc) {
#pragma unroll
            for (int mf = 0; mf < 8; ++mf) {
                f16x8 aFr = *(const f16x8*)(aBaseK[kc] + mf * 4096);
                acc[mf] = __builtin_amdgcn_mfma_f32_16x16x32_f16(aFr, bFu[kc], acc[mf], 0, 0, 0);
            }
        }
        __builtin_amdgcn_s_setprio(0);

        // build NEXT tile's bF while MFMAs drain (independent VALU)
        {
            float gx = bx, gy = by, gz = bz;
            int jn2 = (jt + 2 < 24) ? (jt + 2) : 23;
            const float* pn = pos + (size_t)(b * N_ + jn2 * 16 + ln) * 3;
            bx = pn[0]; by = pn[1]; bz = pn[2];
            makeBF(gx, gy, gz, bFb);
        }

        // phaseC (packed fp16): relu(acc+tj) dot sw; reduce over h4
        unsigned int tju[16] = {tj0.x, tj0.y, tj0.z, tj0.w, tj1.x, tj1.y, tj1.z, tj1.w,
                                tj2.x, tj2.y, tj2.z, tj2.w, tj3.x, tj3.y, tj3.z, tj3.w};
        const f16x2 Z = {(f16)0.f, (f16)0.f};
        f16x2 psA = Z, psB = Z;
#pragma unroll
        for (int mf = 0; mf < 8; ++mf) {
            f16x2 p01 = pk2(acc[mf][0], acc[mf][1]);
            f16x2 p23 = pk2(acc[mf][2], acc[mf][3]);
            f16x2 r01 = __builtin_elementwise_max(p01 + u2h(tju[mf * 2]), Z);
            f16x2 r23 = __builtin_elementwise_max(p23 + u2h(tju[mf * 2 + 1]), Z);
            if (mf < 4) {
                psA = r01 * u2h(swR[mf].x) + (r23 * u2h(swR[mf].y) + psA);
            } else {
                psB = r01 * u2h(swR[mf].x) + (r23 * u2h(swR[mf].y) + psB);
            }
        }
        f16x2 ps = psA + psB;
        float part = (float)ps[0] + (float)ps[1];
        part += __shfl_xor(part, 16);
        part += __shfl_xor(part, 32);
        float sc = part + sb2v;
        if (h4 == 0) scoreRow[j0 + ln] = sc;

        // unshifted exp accumulate
        float a = __expf(sc);
        s_run += a;
        {
            f16 ah = (f16)a;
            f16x2 A2 = {ah, ah};
#pragma unroll
            for (int kc = 0; kc < 4; ++kc) {
                union { f16x8 v; uint4 u; } bc; bc.v = bFu[kc];
                accPh[kc * 4 + 0] = x2u(u2h(bc.u.x) * A2 + u2h(accPh[kc * 4 + 0]));
                accPh[kc * 4 + 1] = x2u(u2h(bc.u.y) * A2 + u2h(accPh[kc * 4 + 1]));
                accPh[kc * 4 + 2] = x2u(u2h(bc.u.z) * A2 + u2h(accPh[kc * 4 + 2]));
                accPh[kc * 4 + 3] = x2u(u2h(bc.u.w) * A2 + u2h(accPh[kc * 4 + 3]));
            }
        }
    };

    // ---- prologue: bFA for tile 0; pos prefetch for tile 1 ----
    f16x8 bFA[4], bFB[4];
    {
        const float* p0 = pos + (size_t)(b * N_ + ln) * 3;
        bx = p0[0]; by = p0[1]; bz = p0[2];
    }
    makeBF(bx, by, bz, bFA);
    {
        const float* p1 = pos + (size_t)(b * N_ + 16 + ln) * 3;
        bx = p1[0]; by = p1[1]; bz = p1[2];
    }

#pragma unroll 1
    for (int t = 0; t < 12; ++t) {
        body(2 * t, bFA, bFB);
        body(2 * t + 1, bFB, bFA);
    }

    // ---- unpack accH to fp32 ----
    float accH[4][8];
#pragma unroll
    for (int kc = 0; kc < 4; ++kc)
#pragma unroll
        for (int p = 0; p < 4; ++p) {
            f16x2 v = u2h(accPh[kc * 4 + p]);
            accH[kc][2 * p] = (float)v[0];
            accH[kc][2 * p + 1] = (float)v[1];
        }

    // ---- epilogue: plain tree sums over ln bits ----
#pragma unroll
    for (int d = 1; d < 16; d <<= 1) {
        s_run += __shfl_xor(s_run, d);
#pragma unroll
        for (int kc = 0; kc < 4; ++kc)
#pragma unroll
            for (int e = 0; e < 8; ++e) accH[kc][e] += __shfl_xor(accH[kc][e], d);
    }
    if (lane == 0) rowsum[b * N_ + i] = s_run;

    // ---- accH @ vW2 (fp32, LDS): lane (ln,h4) dims d=kc*32+h4*8+e -> f=ln*4..+3 ----
    float xp0 = 0.f, xp1 = 0.f, xp2 = 0.f, xp3 = 0.f;
#pragma unroll
    for (int kc = 0; kc < 4; ++kc) {
#pragma unroll
        for (int e = 0; e < 8; ++e) {
            int dIdx = kc * 32 + h4 * 8 + e;
            float av = accH[kc][e];
            float4 wv = *(const float4*)(smem + VW2_OFF + dIdx * 256 + ln * 16);
            xp0 = fmaf(av, wv.x, xp0); xp1 = fmaf(av, wv.y, xp1);
            xp2 = fmaf(av, wv.z, xp2); xp3 = fmaf(av, wv.w, xp3);
        }
    }
    xp0 += __shfl_xor(xp0, 16); xp0 += __shfl_xor(xp0, 32);
    xp1 += __shfl_xor(xp1, 16); xp1 += __shfl_xor(xp1, 32);
    xp2 += __shfl_xor(xp2, 16); xp2 += __shfl_xor(xp2, 32);
    xp3 += __shfl_xor(xp3, 16); xp3 += __shfl_xor(xp3, 32);
    if (h4 == 0) {
        float4 o = {xp0, xp1, xp2, xp3};
        *(float4*)(xpart + (size_t)(b * N_ + i) * F_ + ln * 4) = o;
    }
}

// -------------------- k_xlite: inline batch reduce + att normalize + accI + combine ------
// invT computed per block by reducing rowsum[b][0..N) (L2-cached; replaces k_gred).
// att = exp(sc)*invT; x = 0.5*(xpart*invT + s*vb2) + 0.25*(s*in_i + att@inp)
__global__ __launch_bounds__(256) void k_xlite(
    const float* __restrict__ inp, const float* __restrict__ vb2,
    float* __restrict__ scoresAtt, const float* __restrict__ rowsum,
    const float* __restrict__ xpart, float* __restrict__ xout) {
    int i = blockIdx.x, b = blockIdx.y;
    int tid = threadIdx.x;
    __shared__ float aLds[N_];
    __shared__ float accIp[256];
    __shared__ float tred[64];

    // inline per-batch total: T = sum rowsum[b][*] (fixed tree, deterministic)
    {
        int lane = tid & 63;
        if (tid < 64) {
            float s = 0.f;
#pragma unroll
            for (int k = 0; k < 6; ++k) s += rowsum[b * N_ + lane * 6 + k];
            tred[lane] = s;
        }
        __syncthreads();
        if (tid < 8) {
            float s = tred[tid * 8] + tred[tid * 8 + 1] + tred[tid * 8 + 2] + tred[tid * 8 + 3]
                    + tred[tid * 8 + 4] + tred[tid * 8 + 5] + tred[tid * 8 + 6] + tred[tid * 8 + 7];
            tred[tid] = s;
        }
        __syncthreads();
        if (tid == 0) {
            float T = tred[0] + tred[1] + tred[2] + tred[3] + tred[4] + tred[5] + tred[6] + tred[7];
            tred[0] = 1.f / T;
        }
        __syncthreads();
    }
    const float invTb = tred[0];
    float* scoreRow = scoresAtt + (size_t)(b * N_ + i) * N_;

    {
        float sc = scoreRow[tid];
        float a = __expf(sc) * invTb;
        scoreRow[tid] = a; aLds[tid] = a;
        if (tid < N_ - 256) {
            float sc2 = scoreRow[tid + 256];
            float a2 = __expf(sc2) * invTb;
            scoreRow[tid + 256] = a2; aLds[tid + 256] = a2;
        }
    }
    __syncthreads();

    int f = tid & 63, q = tid >> 6;
    float aI = 0.f;
    const float* inB = inp + (size_t)b * N_ * F_;
    for (int j = q * 96; j < q * 96 + 96; ++j)
        aI = fmaf(aLds[j], inB[j * F_ + f], aI);
    accIp[tid] = aI;
    __syncthreads();

    if (tid < F_) {
        float accI = accIp[tid] + accIp[64 + tid] + accIp[128 + tid] + accIp[192 + tid];
        float s = rowsum[b * N_ + i] * invTb;
        float xp = xpart[(size_t)(b * N_ + i) * F_ + tid] * invTb;
        float r = 0.5f * (xp + s * vb2[tid]) +
                  0.25f * (s * inB[(size_t)i * F_ + tid] + accI);
        xout[(size_t)(b * N_ + i) * F_ + tid] = r;
    }
}

// -------------------- launch --------------------

extern "C" void kernel_launch(void* const* d_in, const int* in_sizes, int n_in,
                              void* d_out, int out_size, void* d_ws, size_t ws_size,
                              hipStream_t stream) {
    const float* inp   = (const float*)d_in[0];
    const float* pos   = (const float*)d_in[1];
    const float* vW1   = (const float*)d_in[2];
    const float* vb1   = (const float*)d_in[3];
    const float* vg    = (const float*)d_in[4];
    const float* vbeta = (const float*)d_in[5];
    const float* vW2   = (const float*)d_in[6];
    const float* vb2   = (const float*)d_in[7];
    const float* sW1   = (const float*)d_in[8];
    const float* sb1   = (const float*)d_in[9];
    const float* sW2   = (const float*)d_in[10];
    const float* sb2   = (const float*)d_in[11];

    float* xout   = (float*)d_out;                 // B*N*F
    float* attout = xout + B_ * N_ * F_;           // B*N*N (scores -> att in place)

    unsigned short* W2hT   = (unsigned short*)d_ws;                  // 32KB fp16
    unsigned int*   coeffP = (unsigned int*)((char*)d_ws + 32768);   // 1KB packed f16x2
    float*          scal   = (float*)((char*)d_ws + 33792);          // 6 scalars (pad)
    unsigned int*   sw16   = (unsigned int*)((char*)d_ws + 34048);   // 64 uints (256B)
    unsigned int*   t16    = (unsigned int*)((char*)d_ws + 34304);   // B*N*64 uints (768KB)
    float* rowsum   = (float*)((char*)d_ws + 34304 + B_ * N_ * 64 * 4);
    float* xpart    = rowsum + B_ * N_;            // B*N*64 fp32 (768KB)

    k_prep<<<B_ * N_ + 128 + 1, 128, 0, stream>>>(
        inp, sW1, vb2, sb1, vW2, vW1, vb1, vg, vbeta, sW2,
        t16, W2hT, coeffP, scal, sw16);
    k_scores<<<dim3(96, B_), 256, 0, stream>>>(
        pos, coeffP, scal, W2hT, vW2, t16, sw16, sb2, attout, rowsum, xpart);
    k_xlite<<<dim3(N_, B_), 256, 0, stream>>>(inp, vb2, attout, rowsum, xpart, xout);
}

// Round 23
// 109.025 us; speedup vs baseline: 7.1380x; 1.0030x over previous
//
#include <hip/hip_runtime.h>
#include <hip/hip_bf16.h>
#include <math.h>

#define B_ 8
#define N_ 384
#define F_ 64
#define H_ 128
#define LN_EPS 1e-5f

typedef _Float16 f16;
typedef f16 f16x2 __attribute__((ext_vector_type(2)));
typedef f16 f16x4 __attribute__((ext_vector_type(4)));
typedef f16 f16x8 __attribute__((ext_vector_type(8)));
typedef float f32x4v __attribute__((ext_vector_type(4)));

static __device__ __forceinline__ f16x2 u2h(unsigned int u) {
    union { unsigned int u; f16x2 h; } c; c.u = u; return c.h;
}
static __device__ __forceinline__ unsigned int h2u(f16 a, f16 b) {
    union { f16x2 h; unsigned int u; } c; c.h = (f16x2){a, b}; return c.u;
}
static __device__ __forceinline__ unsigned int x2u(f16x2 h) {
    union { f16x2 h; unsigned int u; } c; c.h = h; return c.u;
}
// packed f32->f16x2 (round-toward-zero packer, single VALU op)
static __device__ __forceinline__ f16x2 pk2(float a, float b) {
    auto r = __builtin_amdgcn_cvt_pkrtz(a, b);
    union { decltype(r) r; f16x2 h; } c; c.r = r; return c.h;
}

// packed-permuted index helpers: uint slot u = h4*16 + mf*2 + p packs
// elements (n, n+1) with n = mf*16 + h4*4 + 2p  (matches MFMA C/D row layout)
static __device__ __forceinline__ void perm_idx(int m, int& u, int& n0) {
    int h4 = (m >> 1) & 3, mf = m >> 3, p = m & 1;
    u = h4 * 16 + mf * 2 + p;
    n0 = mf * 16 + h4 * 4 + 2 * p;
}

// -------------------- fused setup kernel --------------------
__global__ __launch_bounds__(128) void k_prep(
    const float* __restrict__ inp, const float* __restrict__ sW1,
    const float* __restrict__ vb2, const float* __restrict__ sb1,
    const float* __restrict__ vW2, const float* __restrict__ vW1,
    const float* __restrict__ vb1, const float* __restrict__ vg,
    const float* __restrict__ vbeta, const float* __restrict__ sW2,
    unsigned int* __restrict__ t16, unsigned short* __restrict__ W2hT,
    unsigned int* __restrict__ coeffP, float* __restrict__ scal,
    unsigned int* __restrict__ sw16) {
    __shared__ float red[128];
    __shared__ float caS[128], cbS[128], ccS[128];
    const int bx = blockIdx.x;
    const int tid = threadIdx.x;

    if (bx < B_ * N_) {
        // tt[n] = 0.25*(in[row]+vb2)@sW1[:,n] + 0.5*sb1[n] ; pack-permute to t16
        int row = bx, n = tid;
        float acc = 0.f;
#pragma unroll
        for (int f = 0; f < F_; ++f)
            acc = fmaf(0.25f * (inp[row * F_ + f] + vb2[f]), sW1[f * H_ + n], acc);
        red[n] = acc + 0.5f * sb1[n];
        __syncthreads();
        if (tid < 64) {
            int u, n0; perm_idx(tid, u, n0);
            t16[row * 64 + u] = h2u((f16)red[n0], (f16)red[n0 + 1]);
        }
        return;
    }
    if (bx < B_ * N_ + 128) {
        int idx = (bx - B_ * N_) * 128 + tid;
        int k = idx >> 7, n = idx & 127;
        float acc = 0.f;
#pragma unroll
        for (int f = 0; f < F_; ++f) acc = fmaf(vW2[k * F_ + f], sW1[f * H_ + n], acc);
        f16 hv = (f16)(0.5f * acc);
        W2hT[n * H_ + k] = *reinterpret_cast<unsigned short*>(&hv);
        return;
    }

    // ---- algebraic-LN coefficients + sw16 ----
    const int d = tid;   // 128
    float a = vW1[d], bb = vW1[H_ + d], c = vb1[d];
    float mA, mB, mC, Saa, Sbb, Scc, Sab, Sac, Sbc;
    float ca, cb, cc;
#define BMEAN(OUT, VAL)                                                  \
    red[d] = (VAL); __syncthreads();                                     \
    for (int st = 64; st > 0; st >>= 1) {                                \
        if (d < st) red[d] += red[d + st];                               \
        __syncthreads();                                                 \
    }                                                                    \
    OUT = red[0] * (1.f / 128.f); __syncthreads();

    BMEAN(mA, a); BMEAN(mB, bb); BMEAN(mC, c);
    ca = a - mA; cb = bb - mB; cc = c - mC;
    caS[d] = ca * vg[d]; cbS[d] = cb * vg[d]; ccS[d] = cc * vg[d];
    BMEAN(Saa, ca * ca); BMEAN(Sbb, cb * cb); BMEAN(Scc, cc * cc);
    BMEAN(Sab, ca * cb); BMEAN(Sac, ca * cc); BMEAN(Sbc, cb * cc);
#undef BMEAN
    __syncthreads();
    if (d < 64) {
        int d0 = 2 * d;
        coeffP[d]       = h2u((f16)caS[d0], (f16)caS[d0 + 1]);
        coeffP[64 + d]  = h2u((f16)cbS[d0], (f16)cbS[d0 + 1]);
        coeffP[128 + d] = h2u((f16)ccS[d0], (f16)ccS[d0 + 1]);
        coeffP[192 + d] = h2u((f16)vbeta[d0], (f16)vbeta[d0 + 1]);
        int u, n0; perm_idx(d, u, n0);
        sw16[u] = h2u((f16)sW2[n0], (f16)sW2[n0 + 1]);
    }
    if (d == 0) {
        scal[0] = Saa; scal[1] = Sbb; scal[2] = Scc;
        scal[3] = Sab; scal[4] = Sac; scal[5] = Sbc;
    }
}

// -------------------- phase 1: scores + unshifted-exp accH (phaseC chain split) ---------
// R22 base (setprio MFMA cluster, hoisted LDS bases, ping-pong bF, packed-fp16 phaseC,
// unshifted exp, fused accH). NEW: phaseC uses FOUR independent partial accumulators
// (halves the dependent packed-FMA chain that dominated the per-tile stall tail).
#define VW2_OFF 32768
__global__ __launch_bounds__(256) void k_scores(
    const float* __restrict__ pos, const unsigned int* __restrict__ coeffP,
    const float* __restrict__ scal, const unsigned short* __restrict__ W2hT,
    const float* __restrict__ vW2, const unsigned int* __restrict__ t16,
    const unsigned int* __restrict__ sw16, const float* __restrict__ sb2,
    float* __restrict__ scores, float* __restrict__ rowsum,
    float* __restrict__ xpart) {
    __shared__ __align__(16) char smem[65536];   // 32KB W' (swizzled) + 32KB vW2 fp32

    const int tid = threadIdx.x;
    const int b = blockIdx.y;
    const int w = tid >> 6, lane = tid & 63;
    const int i = blockIdx.x * 4 + w;
    const int ln = lane & 15, h4 = lane >> 4;

    // ---- one-time stage: W' swizzled + vW2 fp32 ----
#pragma unroll
    for (int s = 0; s < 8; ++s) {
        int idx = tid + s * 256;
        int n = idx >> 4, c = idx & 15;
        uint4 v = *(const uint4*)(W2hT + n * H_ + c * 8);
        *(uint4*)(smem + ((n * 256 + c * 16) ^ ((n & 7) << 4))) = v;
    }
#pragma unroll
    for (int s = 0; s < 8; ++s) {
        int idx = tid + s * 256;            // 0..2047 float4 chunks of vW2 (128x64)
        uint4 v = *(const uint4*)((const float*)vW2 + idx * 4);
        *(uint4*)(smem + VW2_OFF + idx * 16) = v;
    }
    __syncthreads();

    // ---- resident state ----
    uint4 cagR[4], cbgR[4], ccgR[4], vbR[4];
#pragma unroll
    for (int kc = 0; kc < 4; ++kc) {
        cagR[kc] = *(const uint4*)(coeffP + kc * 16 + h4 * 4);
        cbgR[kc] = *(const uint4*)(coeffP + 64 + kc * 16 + h4 * 4);
        ccgR[kc] = *(const uint4*)(coeffP + 128 + kc * 16 + h4 * 4);
        vbR[kc]  = *(const uint4*)(coeffP + 192 + kc * 16 + h4 * 4);
    }
    // acc-init (= ti) resident in fp32 — consumed as the kc=0 MFMA C operand
    f32x4v acc0[8];
    {
        const unsigned int* tiP = t16 + (size_t)(b * N_ + i) * 64 + h4 * 16;
#pragma unroll
        for (int s = 0; s < 4; ++s) {
            uint4 v = *(const uint4*)(tiP + s * 4);
            f16x2 a0 = u2h(v.x), a1 = u2h(v.y), a2 = u2h(v.z), a3 = u2h(v.w);
            acc0[s * 2][0] = (float)a0[0]; acc0[s * 2][1] = (float)a0[1];
            acc0[s * 2][2] = (float)a1[0]; acc0[s * 2][3] = (float)a1[1];
            acc0[s * 2 + 1][0] = (float)a2[0]; acc0[s * 2 + 1][1] = (float)a2[1];
            acc0[s * 2 + 1][2] = (float)a3[0]; acc0[s * 2 + 1][3] = (float)a3[1];
        }
    }
    uint2 swR[8];
#pragma unroll
    for (int mf = 0; mf < 8; ++mf)
        swR[mf] = *(const uint2*)(sw16 + h4 * 16 + mf * 2);

    const float Saa = scal[0], Sbb = scal[1], Scc = scal[2];
    const float Sab = scal[3], Sac = scal[4], Sbc = scal[5];
    const float sb2v = sb2[0];

    const float* pi = pos + (size_t)(b * N_ + i) * 3;
    const float ax = pi[0], ay = pi[1], az = pi[2];
    float* scoreRow = scores + (size_t)(b * N_ + i) * N_;

    // hoisted LDS A-read bases (loop-invariant)
    const char* aBaseK[4];
#pragma unroll
    for (int kc = 0; kc < 4; ++kc)
        aBaseK[kc] = smem + ln * 256 + ((kc * 64 + h4 * 16) ^ ((ln & 7) << 4));

    float s_run = 0.f;
    unsigned int accPh[16];                    // packed f16x2 accH (kc*4 + e/2)
#pragma unroll
    for (int k = 0; k < 16; ++k) accPh[k] = 0u;

    // bF construction from a given j-pos (uses resident coeffs)
    auto makeBF = [&](float bx_, float by_, float bz_, f16x8 (&bF)[4]) {
        float dotv = ax * bx_ + ay * by_ + az * bz_;
        float cx = ay * bz_ - az * by_;
        float cy = az * bx_ - ax * bz_;
        float cz = ax * by_ - ay * bx_;
        float cns = cx * cx + cy * cy + cz * cz;
        float cn = sqrtf(cns);
        float var = Saa * dotv * dotv + Sbb * cns + Scc +
                    2.f * (Sab * dotv * cn + Sac * dotv + Sbc * cn);
        float rstd = rsqrtf(var + LN_EPS);
        f16 d2 = (f16)(dotv * rstd), c2 = (f16)(cn * rstd), r2 = (f16)rstd;
        f16x2 D2 = {d2, d2}, C2 = {c2, c2}, R2 = {r2, r2};
        const f16x2 Z = {(f16)0.f, (f16)0.f};
#pragma unroll
        for (int kc = 0; kc < 4; ++kc) {
            f16x2 vp0 = __builtin_elementwise_max(D2 * u2h(cagR[kc].x) + (C2 * u2h(cbgR[kc].x) + (R2 * u2h(ccgR[kc].x) + u2h(vbR[kc].x))), Z);
            f16x2 vp1 = __builtin_elementwise_max(D2 * u2h(cagR[kc].y) + (C2 * u2h(cbgR[kc].y) + (R2 * u2h(ccgR[kc].y) + u2h(vbR[kc].y))), Z);
            f16x2 vp2 = __builtin_elementwise_max(D2 * u2h(cagR[kc].z) + (C2 * u2h(cbgR[kc].z) + (R2 * u2h(ccgR[kc].z) + u2h(vbR[kc].z))), Z);
            f16x2 vp3 = __builtin_elementwise_max(D2 * u2h(cagR[kc].w) + (C2 * u2h(cbgR[kc].w) + (R2 * u2h(ccgR[kc].w) + u2h(vbR[kc].w))), Z);
            f16x4 q01 = __builtin_shufflevector(vp0, vp1, 0, 1, 2, 3);
            f16x4 q23 = __builtin_shufflevector(vp2, vp3, 0, 1, 2, 3);
            bF[kc] = __builtin_shufflevector(q01, q23, 0, 1, 2, 3, 4, 5, 6, 7);
        }
    };

    // per-tile body: GEMM with bFu (kc0 C=acc0), build bFb for tile jt+1,
    // pos prefetch for jt+2, phaseC (4 independent chains), exp+accH with bFu.
    float bx, by, bz;
    auto body = [&](int jt, f16x8 (&bFu)[4], f16x8 (&bFb)[4]) {
        const int j0 = jt * 16;

        // tj prefetch (packed), consumed at phaseC
        const unsigned int* tjP = t16 + (size_t)(b * N_ + j0 + ln) * 64 + h4 * 16;
        uint4 tj0 = *(const uint4*)(tjP);
        uint4 tj1 = *(const uint4*)(tjP + 4);
        uint4 tj2 = *(const uint4*)(tjP + 8);
        uint4 tj3 = *(const uint4*)(tjP + 12);

        // GEMM: kc=0 uses acc0 as C (free init); kc=1..3 accumulate
        __builtin_amdgcn_s_setprio(1);
        f32x4v acc[8];
#pragma unroll
        for (int mf = 0; mf < 8; ++mf) {
            f16x8 aFr = *(const f16x8*)(aBaseK[0] + mf * 4096);
            acc[mf] = __builtin_amdgcn_mfma_f32_16x16x32_f16(aFr, bFu[0], acc0[mf], 0, 0, 0);
        }
#pragma unroll
        for (int kc = 1; kc < 4; ++kc) {
#pragma unroll
            for (int mf = 0; mf < 8; ++mf) {
                f16x8 aFr = *(const f16x8*)(aBaseK[kc] + mf * 4096);
                acc[mf] = __builtin_amdgcn_mfma_f32_16x16x32_f16(aFr, bFu[kc], acc[mf], 0, 0, 0);
            }
        }
        __builtin_amdgcn_s_setprio(0);

        // build NEXT tile's bF while MFMAs drain (independent VALU)
        {
            float gx = bx, gy = by, gz = bz;
            int jn2 = (jt + 2 < 24) ? (jt + 2) : 23;
            const float* pn = pos + (size_t)(b * N_ + jn2 * 16 + ln) * 3;
            bx = pn[0]; by = pn[1]; bz = pn[2];
            makeBF(gx, gy, gz, bFb);
        }

        // phaseC (packed fp16): relu(acc+tj) dot sw; 4 independent chains
        unsigned int tju[16] = {tj0.x, tj0.y, tj0.z, tj0.w, tj1.x, tj1.y, tj1.z, tj1.w,
                                tj2.x, tj2.y, tj2.z, tj2.w, tj3.x, tj3.y, tj3.z, tj3.w};
        const f16x2 Z = {(f16)0.f, (f16)0.f};
        f16x2 ps0 = Z, ps1 = Z, ps2 = Z, ps3 = Z;
#pragma unroll
        for (int mf = 0; mf < 8; ++mf) {
            f16x2 p01 = pk2(acc[mf][0], acc[mf][1]);
            f16x2 p23 = pk2(acc[mf][2], acc[mf][3]);
            f16x2 r01 = __builtin_elementwise_max(p01 + u2h(tju[mf * 2]), Z);
            f16x2 r23 = __builtin_elementwise_max(p23 + u2h(tju[mf * 2 + 1]), Z);
            switch (mf & 3) {
                case 0: ps0 = r01 * u2h(swR[mf].x) + (r23 * u2h(swR[mf].y) + ps0); break;
                case 1: ps1 = r01 * u2h(swR[mf].x) + (r23 * u2h(swR[mf].y) + ps1); break;
                case 2: ps2 = r01 * u2h(swR[mf].x) + (r23 * u2h(swR[mf].y) + ps2); break;
                default: ps3 = r01 * u2h(swR[mf].x) + (r23 * u2h(swR[mf].y) + ps3); break;
            }
        }
        f16x2 ps = (ps0 + ps1) + (ps2 + ps3);
        float part = (float)ps[0] + (float)ps[1];
        part += __shfl_xor(part, 16);
        part += __shfl_xor(part, 32);
        float sc = part + sb2v;
        if (h4 == 0) scoreRow[j0 + ln] = sc;

        // unshifted exp accumulate
        float a = __expf(sc);
        s_run += a;
        {
            f16 ah = (f16)a;
            f16x2 A2 = {ah, ah};
#pragma unroll
            for (int kc = 0; kc < 4; ++kc) {
                union { f16x8 v; uint4 u; } bc; bc.v = bFu[kc];
                accPh[kc * 4 + 0] = x2u(u2h(bc.u.x) * A2 + u2h(accPh[kc * 4 + 0]));
                accPh[kc * 4 + 1] = x2u(u2h(bc.u.y) * A2 + u2h(accPh[kc * 4 + 1]));
                accPh[kc * 4 + 2] = x2u(u2h(bc.u.z) * A2 + u2h(accPh[kc * 4 + 2]));
                accPh[kc * 4 + 3] = x2u(u2h(bc.u.w) * A2 + u2h(accPh[kc * 4 + 3]));
            }
        }
    };

    // ---- prologue: bFA for tile 0; pos prefetch for tile 1 ----
    f16x8 bFA[4], bFB[4];
    {
        const float* p0 = pos + (size_t)(b * N_ + ln) * 3;
        bx = p0[0]; by = p0[1]; bz = p0[2];
    }
    makeBF(bx, by, bz, bFA);
    {
        const float* p1 = pos + (size_t)(b * N_ + 16 + ln) * 3;
        bx = p1[0]; by = p1[1]; bz = p1[2];
    }

#pragma unroll 1
    for (int t = 0; t < 12; ++t) {
        body(2 * t, bFA, bFB);
        body(2 * t + 1, bFB, bFA);
    }

    // ---- unpack accH to fp32 ----
    float accH[4][8];
#pragma unroll
    for (int kc = 0; kc < 4; ++kc)
#pragma unroll
        for (int p = 0; p < 4; ++p) {
            f16x2 v = u2h(accPh[kc * 4 + p]);
            accH[kc][2 * p] = (float)v[0];
            accH[kc][2 * p + 1] = (float)v[1];
        }

    // ---- epilogue: plain tree sums over ln bits ----
#pragma unroll
    for (int d = 1; d < 16; d <<= 1) {
        s_run += __shfl_xor(s_run, d);
#pragma unroll
        for (int kc = 0; kc < 4; ++kc)
#pragma unroll
            for (int e = 0; e < 8; ++e) accH[kc][e] += __shfl_xor(accH[kc][e], d);
    }
    if (lane == 0) rowsum[b * N_ + i] = s_run;

    // ---- accH @ vW2 (fp32, LDS): lane (ln,h4) dims d=kc*32+h4*8+e -> f=ln*4..+3 ----
    float xp0 = 0.f, xp1 = 0.f, xp2 = 0.f, xp3 = 0.f;
#pragma unroll
    for (int kc = 0; kc < 4; ++kc) {
#pragma unroll
        for (int e = 0; e < 8; ++e) {
            int dIdx = kc * 32 + h4 * 8 + e;
            float av = accH[kc][e];
            float4 wv = *(const float4*)(smem + VW2_OFF + dIdx * 256 + ln * 16);
            xp0 = fmaf(av, wv.x, xp0); xp1 = fmaf(av, wv.y, xp1);
            xp2 = fmaf(av, wv.z, xp2); xp3 = fmaf(av, wv.w, xp3);
        }
    }
    xp0 += __shfl_xor(xp0, 16); xp0 += __shfl_xor(xp0, 32);
    xp1 += __shfl_xor(xp1, 16); xp1 += __shfl_xor(xp1, 32);
    xp2 += __shfl_xor(xp2, 16); xp2 += __shfl_xor(xp2, 32);
    xp3 += __shfl_xor(xp3, 16); xp3 += __shfl_xor(xp3, 32);
    if (h4 == 0) {
        float4 o = {xp0, xp1, xp2, xp3};
        *(float4*)(xpart + (size_t)(b * N_ + i) * F_ + ln * 4) = o;
    }
}

// -------------------- k_xlite: inline batch reduce + att normalize + accI + combine ------
__global__ __launch_bounds__(256) void k_xlite(
    const float* __restrict__ inp, const float* __restrict__ vb2,
    float* __restrict__ scoresAtt, const float* __restrict__ rowsum,
    const float* __restrict__ xpart, float* __restrict__ xout) {
    int i = blockIdx.x, b = blockIdx.y;
    int tid = threadIdx.x;
    __shared__ float aLds[N_];
    __shared__ float accIp[256];
    __shared__ float tred[64];

    // inline per-batch total: T = sum rowsum[b][*] (fixed tree, deterministic)
    {
        int lane = tid & 63;
        if (tid < 64) {
            float s = 0.f;
#pragma unroll
            for (int k = 0; k < 6; ++k) s += rowsum[b * N_ + lane * 6 + k];
            tred[lane] = s;
        }
        __syncthreads();
        if (tid < 8) {
            float s = tred[tid * 8] + tred[tid * 8 + 1] + tred[tid * 8 + 2] + tred[tid * 8 + 3]
                    + tred[tid * 8 + 4] + tred[tid * 8 + 5] + tred[tid * 8 + 6] + tred[tid * 8 + 7];
            tred[tid] = s;
        }
        __syncthreads();
        if (tid == 0) {
            float T = tred[0] + tred[1] + tred[2] + tred[3] + tred[4] + tred[5] + tred[6] + tred[7];
            tred[0] = 1.f / T;
        }
        __syncthreads();
    }
    const float invTb = tred[0];
    float* scoreRow = scoresAtt + (size_t)(b * N_ + i) * N_;

    {
        float sc = scoreRow[tid];
        float a = __expf(sc) * invTb;
        scoreRow[tid] = a; aLds[tid] = a;
        if (tid < N_ - 256) {
            float sc2 = scoreRow[tid + 256];
            float a2 = __expf(sc2) * invTb;
            scoreRow[tid + 256] = a2; aLds[tid + 256] = a2;
        }
    }
    __syncthreads();

    int f = tid & 63, q = tid >> 6;
    float aI = 0.f;
    const float* inB = inp + (size_t)b * N_ * F_;
    for (int j = q * 96; j < q * 96 + 96; ++j)
        aI = fmaf(aLds[j], inB[j * F_ + f], aI);
    accIp[tid] = aI;
    __syncthreads();

    if (tid < F_) {
        float accI = accIp[tid] + accIp[64 + tid] + accIp[128 + tid] + accIp[192 + tid];
        float s = rowsum[b * N_ + i] * invTb;
        float xp = xpart[(size_t)(b * N_ + i) * F_ + tid] * invTb;
        float r = 0.5f * (xp + s * vb2[tid]) +
                  0.25f * (s * inB[(size_t)i * F_ + tid] + accI);
        xout[(size_t)(b * N_ + i) * F_ + tid] = r;
    }
}

// -------------------- launch --------------------

extern "C" void kernel_launch(void* const* d_in, const int* in_sizes, int n_in,
                              void* d_out, int out_size, void* d_ws, size_t ws_size,
                              hipStream_t stream) {
    const float* inp   = (const float*)d_in[0];
    const float* pos   = (const float*)d_in[1];
    const float* vW1   = (const float*)d_in[2];
    const float* vb1   = (const float*)d_in[3];
    const float* vg    = (const float*)d_in[4];
    const float* vbeta = (const float*)d_in[5];
    const float* vW2   = (const float*)d_in[6];
    const float* vb2   = (const float*)d_in[7];
    const float* sW1   = (const float*)d_in[8];
    const float* sb1   = (const float*)d_in[9];
    const float* sW2   = (const float*)d_in[10];
    const float* sb2   = (const float*)d_in[11];

    float* xout   = (float*)d_out;                 // B*N*F
    float* attout = xout + B_ * N_ * F_;           // B*N*N (scores -> att in place)

    unsigned short* W2hT   = (unsigned short*)d_ws;                  // 32KB fp16
    unsigned int*   coeffP = (unsigned int*)((char*)d_ws + 32768);   // 1KB packed f16x2
    float*          scal   = (float*)((char*)d_ws + 33792);          // 6 scalars (pad)
    unsigned int*   sw16   = (unsigned int*)((char*)d_ws + 34048);   // 64 uints (256B)
    unsigned int*   t16    = (unsigned int*)((char*)d_ws + 34304);   // B*N*64 uints (768KB)
    float* rowsum   = (float*)((char*)d_ws + 34304 + B_ * N_ * 64 * 4);
    float* xpart    = rowsum + B_ * N_;            // B*N*64 fp32 (768KB)

    k_prep<<<B_ * N_ + 128 + 1, 128, 0, stream>>>(
        inp, sW1, vb2, sb1, vW2, vW1, vb1, vg, vbeta, sW2,
        t16, W2hT, coeffP, scal, sw16);
    k_scores<<<dim3(96, B_), 256, 0, stream>>>(
        pos, coeffP, scal, W2hT, vW2, t16, sw16, sb2, attout, rowsum, xpart);
    k_xlite<<<dim3(N_, B_), 256, 0, stream>>>(inp, vb2, attout, rowsum, xpart, xout);
}